// Round 6
// baseline (462.118 us; speedup 1.0000x reference)
//
#include <hip/hip_runtime.h>
#include <math.h>

#define NN 100000
#define EE 1600000
#define ET (EE + NN)          // edges + self loops = 1,700,000
#define NEG 0.2f
#define MSTR 68               // k_mlp LDS row stride (floats)
#define SL  (NN * 8)          // xps slice stride (floats): 8 channels per slice
#define SL4 (NN * 2)          // slice stride in float4 units

// CSR-build geometry
#define NBUCK 98              // ceil(NN/1024) buckets of 1024 dst nodes
#define NBLK 416              // ceil(ET/4096) partition blocks
#define BITEMS 4096           // items per partition block (256 thr x 16)

typedef float4 f4;

// ---------------- init: stats=0 ----------------
__global__ void k_init(float* stats) {
    int i = threadIdx.x;
    if (i < 4) stats[i] = 0.f;
}

// ---------------- BN statistics: sum / sumsq of 2 columns ----------------
__global__ void k_bnstats(const float* __restrict__ h, float* stats) {
    int gid = blockIdx.x * blockDim.x + threadIdx.x;
    int stride = gridDim.x * blockDim.x;
    float s0 = 0.f, s1 = 0.f, q0 = 0.f, q1 = 0.f;
    for (int i = gid; i < NN; i += stride) {
        float2 v = reinterpret_cast<const float2*>(h)[i];
        s0 += v.x; q0 += v.x * v.x;
        s1 += v.y; q1 += v.y * v.y;
    }
#pragma unroll
    for (int off = 32; off >= 1; off >>= 1) {
        s0 += __shfl_xor(s0, off);
        s1 += __shfl_xor(s1, off);
        q0 += __shfl_xor(q0, off);
        q1 += __shfl_xor(q1, off);
    }
    if ((threadIdx.x & 63) == 0) {
        atomicAdd(&stats[0], s0); atomicAdd(&stats[1], s1);
        atomicAdd(&stats[2], q0); atomicAdd(&stats[3], q1);
    }
}

// ---------------- rank-2 attention coefficients ----------------
__global__ void k_coef(const float* __restrict__ W1, const float* __restrict__ as1,
                       const float* __restrict__ ad1, float* __restrict__ coef) {
    int t = threadIdx.x;
    if (t >= 8) return;
    int sd = t >> 2, hh = (t >> 1) & 1, i = t & 1;
    const float* a = sd ? ad1 : as1;
    float s = 0.f;
    for (int c = 0; c < 32; ++c) s += W1[(hh * 32 + c) * 2 + i] * a[hh * 32 + c];
    coef[t] = s;
}

// ---------------- pack MLP weights for wave-uniform contiguous s_load streams ----------------
__global__ void k_wprep(const float* __restrict__ w1, const float* __restrict__ w2,
                        const float* __restrict__ w3, const float* __restrict__ w4,
                        const float* __restrict__ w5,
                        float* __restrict__ Wt, float* __restrict__ Wt5) {
    int idx = blockIdx.x * blockDim.x + threadIdx.x;
    if (idx < 4 * 4096) {
        int L = idx >> 12;
        int r = idx & 4095;
        int q = r >> 10;
        int t = r & 1023;
        int i = t >> 4, j = t & 15;
        const float* W = (L == 0) ? w1 : (L == 1) ? w2 : (L == 2) ? w3 : w4;
        Wt[idx] = W[(q * 16 + j) * 64 + i];
    }
    if (idx < 1024) {
        int i = idx >> 4, c = idx & 15;
        int w = c >> 2, j = c & 3;
        int o = 3 * w + j;
        int ocnt = (w == 3) ? 2 : 3;
        Wt5[idx] = (j < ocnt) ? w5[o * 64 + i] : 0.f;
    }
}

// ---------------- CSR pass A: per-block bucket histogram ----------------
__global__ void __launch_bounds__(256) k_hist(const int* __restrict__ ei, int* __restrict__ H) {
    __shared__ int hist[NBUCK];
    int tid = threadIdx.x, blk = blockIdx.x;
    if (tid < NBUCK) hist[tid] = 0;
    __syncthreads();
    int base = blk * BITEMS;
#pragma unroll
    for (int it = 0; it < 16; ++it) {
        int i = base + it * 256 + tid;
        if (i < ET) {
            int d = (i < EE) ? ei[EE + i] : (i - EE);
            atomicAdd(&hist[d >> 10], 1);
        }
    }
    __syncthreads();
    if (tid < NBUCK) H[tid * NBLK + blk] = hist[tid];
}

// ---------------- CSR pass B1: bucket totals + base offsets (1 block) ----------------
__global__ void __launch_bounds__(1024) k_bscan1(const int* __restrict__ H, int* __restrict__ boff) {
    __shared__ int part[1024];
    __shared__ int btot[NBUCK];
    int tid = threadIdx.x;
    int b = tid >> 3, k = tid & 7;
    int s = 0;
    if (b < NBUCK)
        for (int blk = k; blk < NBLK; blk += 8) s += H[b * NBLK + blk];
    part[tid] = s;
    __syncthreads();
    if (tid < NBUCK) {
        int t = 0;
#pragma unroll
        for (int j = 0; j < 8; ++j) t += part[tid * 8 + j];
        btot[tid] = t;
    }
    __syncthreads();
    if (tid == 0) {
        int run = 0;
        for (int bb = 0; bb < NBUCK; ++bb) { boff[bb] = run; run += btot[bb]; }
        boff[NBUCK] = ET;
    }
}

// ---------------- CSR pass B2: per-(bucket,block) absolute offsets ----------------
__global__ void __launch_bounds__(64) k_bscan2(int* __restrict__ H, const int* __restrict__ boff) {
    int b = blockIdx.x, lane = threadIdx.x;
    int s = 0;
    int base_i = lane * 7;
#pragma unroll
    for (int j = 0; j < 7; ++j) {
        int idx = base_i + j;
        if (idx < NBLK) s += H[b * NBLK + idx];
    }
    int incl = s;
#pragma unroll
    for (int d = 1; d < 64; d <<= 1) {
        int n = __shfl_up(incl, d, 64);
        if (lane >= d) incl += n;
    }
    int run = boff[b] + incl - s;
#pragma unroll
    for (int j = 0; j < 7; ++j) {
        int idx = base_i + j;
        if (idx < NBLK) {
            int t = H[b * NBLK + idx];
            H[b * NBLK + idx] = run;
            run += t;
        }
    }
}

// ---------------- CSR pass C: partition edges into bucket regions ----------------
__global__ void __launch_bounds__(256) k_part(const int* __restrict__ ei, const int* __restrict__ H,
                                              unsigned* __restrict__ pairs) {
    __shared__ int cur[NBUCK];
    int tid = threadIdx.x, blk = blockIdx.x;
    if (tid < NBUCK) cur[tid] = H[tid * NBLK + blk];
    __syncthreads();
    int base = blk * BITEMS;
#pragma unroll
    for (int it = 0; it < 16; ++it) {
        int i = base + it * 256 + tid;
        if (i < ET) {
            int s, d;
            if (i < EE) { s = ei[i]; d = ei[EE + i]; }
            else { s = d = i - EE; }
            int b = d >> 10;
            int pos = atomicAdd(&cur[b], 1);
            pairs[pos] = (unsigned)s | ((unsigned)(d & 1023) << 17);
        }
    }
}

// ---------------- CSR pass D: per-bucket local CSR (rowptr + srcl) ----------------
__global__ void __launch_bounds__(1024) k_bucket(const unsigned* __restrict__ pairs,
                                                 const int* __restrict__ boff,
                                                 int* __restrict__ rowptr, int* __restrict__ srcl) {
    __shared__ int sh[1024];
    __shared__ int se[1024];
    int b = blockIdx.x, tid = threadIdx.x;
    int bb = boff[b], be = boff[b + 1];
    sh[tid] = 0;
    __syncthreads();
    for (int k = bb + tid; k < be; k += 1024) atomicAdd(&sh[pairs[k] >> 17], 1);
    __syncthreads();
    int deg = sh[tid];
    se[tid] = deg;
    __syncthreads();
    for (int off = 1; off < 1024; off <<= 1) {
        int t = (tid >= off) ? se[tid - off] : 0;
        __syncthreads();
        se[tid] += t;
        __syncthreads();
    }
    int excl = se[tid] - deg;
    int node = (b << 10) + tid;
    if (node < NN) rowptr[node] = bb + excl;
    sh[tid] = bb + excl;     // cursor
    __syncthreads();
    for (int k = bb + tid; k < be; k += 1024) {
        unsigned p = pairs[k];
        int pos = atomicAdd(&sh[p >> 17], 1);
        srcl[pos] = (int)(p & 0x1FFFFu);
    }
    if (b == 0 && tid == 0) rowptr[NN] = ET;
}

// ---------------- layer-1 prep: BN apply + rank-2 attention scalars ----------------
__global__ void k_prep1(const float* __restrict__ h, const float* __restrict__ stats,
                        const float* __restrict__ gamma, const float* __restrict__ beta,
                        const float* __restrict__ coef,
                        f4* __restrict__ nd1, float2* __restrict__ ed1) {
    int n = blockIdx.x * blockDim.x + threadIdx.x;
    if (n >= NN) return;
    const float inv = 1.f / (float)NN;
    float mu0 = stats[0] * inv, mu1 = stats[1] * inv;
    float v0 = stats[2] * inv - mu0 * mu0;
    float v1 = stats[3] * inv - mu1 * mu1;
    float g0 = rsqrtf(v0 + 1e-5f) * gamma[0];
    float g1 = rsqrtf(v1 + 1e-5f) * gamma[1];
    float2 hv = reinterpret_cast<const float2*>(h)[n];
    float x0 = (hv.x - mu0) * g0 + beta[0];
    float x1 = (hv.y - mu1) * g1 + beta[1];
    float es0 = x0 * coef[0] + x1 * coef[1];
    float es1 = x0 * coef[2] + x1 * coef[3];
    float ed0 = x0 * coef[4] + x1 * coef[5];
    float ed1v = x0 * coef[6] + x1 * coef[7];
    nd1[n] = make_float4(es0, es1, x0, x1);
    ed1[n] = make_float2(ed0, ed1v);
}

// ---------------- layer-1 GAT: thread per dst node, 16B gather (L2-resident 1.6MB) ----------------
__global__ void __launch_bounds__(256) k_gat1(
    const f4* __restrict__ nd1, const float2* __restrict__ ed1,
    const int* __restrict__ rowptr, const int* __restrict__ srcl,
    f4* __restrict__ agg1a, float2* __restrict__ agg1s) {
    int n = blockIdx.x * blockDim.x + threadIdx.x;
    if (n >= NN) return;
    int beg = rowptr[n], end = rowptr[n + 1];
    float2 ed = ed1[n];
    float A0 = 0.f, B0 = 0.f, S0 = 0.f, A1 = 0.f, B1 = 0.f, S1 = 0.f;
    for (int k = beg; k < end; ++k) {
        int s = srcl[k];
        f4 p = nd1[s];
        float e0 = p.x + ed.x;
        float e1 = p.y + ed.y;
        e0 = (e0 > 0.f) ? e0 : NEG * e0;
        e1 = (e1 > 0.f) ? e1 : NEG * e1;
        float w0 = __expf(e0);
        float w1 = __expf(e1);
        A0 += w0 * p.z; B0 += w0 * p.w; S0 += w0;
        A1 += w1 * p.z; B1 += w1 * p.w; S1 += w1;
    }
    agg1a[n] = make_float4(A0, B0, A1, B1);
    agg1s[n] = make_float2(S0, S1);
}

// ---------------- layer-1 finalize + linear(64->64); writes SLICED xps + per-head es/ed ----------------
// xps[g*SL + n*8 + c] (g<8, c<8); es_s[head*NN+n]; ed_s[head*NN+n]
__global__ void k_xform2f(const f4* __restrict__ agg1a, const float2* __restrict__ agg1s,
                          const float* __restrict__ W1, const float* __restrict__ b1,
                          const float* __restrict__ W, const float* __restrict__ a_s,
                          const float* __restrict__ a_d,
                          float* __restrict__ xps, float* __restrict__ es_s,
                          float* __restrict__ ed_s) {
    int n = blockIdx.x * blockDim.x + threadIdx.x;
    if (n >= NN) return;
    f4 ag = agg1a[n];
    float2 sg = agg1s[n];
    float r0 = 1.f / (sg.x + 1e-16f);
    float r1 = 1.f / (sg.y + 1e-16f);
    float x[64];
#pragma unroll
    for (int f = 0; f < 64; ++f) {
        float A = (f < 32) ? ag.x : ag.z;
        float B = (f < 32) ? ag.y : ag.w;
        float r = (f < 32) ? r0 : r1;
        x[f] = fmaxf((A * W1[2 * f] + B * W1[2 * f + 1]) * r + b1[f], 0.f);
    }
    float es0 = 0.f, es1 = 0.f, ed0 = 0.f, ed1 = 0.f;
    f4* xo = reinterpret_cast<f4*>(xps);
#pragma unroll 1
    for (int fq = 0; fq < 16; ++fq) {
        float vq[4];
#pragma unroll
        for (int j = 0; j < 4; ++j) {
            int f = 4 * fq + j;
            float acc = 0.f;
#pragma unroll
            for (int i = 0; i < 64; ++i) acc += W[f * 64 + i] * x[i];
            vq[j] = acc;
            float ts = acc * a_s[f], td = acc * a_d[f];
            if (fq < 8) { es0 += ts; ed0 += td; } else { es1 += ts; ed1 += td; }
        }
        int g = fq >> 1, half = fq & 1;
        xo[(size_t)g * SL4 + n * 2 + half] = make_float4(vq[0], vq[1], vq[2], vq[3]);
    }
    es_s[n] = es0; es_s[NN + n] = es1;
    ed_s[n] = ed0; ed_s[NN + n] = ed1;
}

// ---------------- layer-2 GAT: channel-sliced, XCD-affine (group = blockIdx%8) ----------------
// Each block: 4 waves x 8 dst-octets; lane = oct*8+ch. Slice g is L2-resident (3.2MB/XCD).
__global__ void __launch_bounds__(256) k_gat2(
    const float* __restrict__ xps, const float* __restrict__ es_s, const float* __restrict__ ed_s,
    const int* __restrict__ rowptr, const int* __restrict__ srcl,
    const float* __restrict__ bias, float* __restrict__ out_s) {
    int g = blockIdx.x & 7;            // channel group -> XCD (round-robin dispatch)
    int chunk = blockIdx.x >> 3;       // dst chunk within group
    int wv = threadIdx.x >> 6;
    int lane = threadIdx.x & 63;
    int oct = lane >> 3, ch = lane & 7;
    int dst = chunk * 32 + wv * 8 + oct;           // 3125*32 = 100000 exactly
    int hgNN = (g >> 2) * NN;                      // head offset
    const float* xg = xps + (size_t)g * SL;
    int beg = rowptr[dst], end = rowptr[dst + 1];
    float edv = ed_s[hgNN + dst];
    float sum = 0.f, acc = 0.f;
    int k = beg;
    for (; k + 2 <= end; k += 2) {
        int s0 = __builtin_nontemporal_load(&srcl[k]);
        int s1 = __builtin_nontemporal_load(&srcl[k + 1]);
        float e0 = es_s[hgNN + s0] + edv;
        float e1 = es_s[hgNN + s1] + edv;
        float x0 = xg[s0 * 8 + ch];
        float x1 = xg[s1 * 8 + ch];
        e0 = (e0 > 0.f) ? e0 : NEG * e0;
        e1 = (e1 > 0.f) ? e1 : NEG * e1;
        float w0 = __expf(e0);
        float w1 = __expf(e1);
        sum += w0 + w1;
        acc += w0 * x0 + w1 * x1;
    }
    if (k < end) {
        int s = __builtin_nontemporal_load(&srcl[k]);
        float e = es_s[hgNN + s] + edv;
        e = (e > 0.f) ? e : NEG * e;
        float w = __expf(e);
        sum += w;
        acc += w * xg[s * 8 + ch];
    }
    float r = acc / (sum + 1e-16f) + bias[g * 8 + ch];
    // sliced output, coalesced 256B per wave, nontemporal to keep xps resident
    __builtin_nontemporal_store(fmaxf(r, 0.f), &out_s[(size_t)g * SL + dst * 8 + ch]);
}

// ---------------- fused 5-layer MLP (input in sliced layout) ----------------
__device__ __forceinline__ void mlayer(const float* __restrict__ Wq, const float* __restrict__ B,
                                       int o0, const float* __restrict__ xrow, float* acc) {
#pragma unroll
    for (int j = 0; j < 16; ++j) acc[j] = B[o0 + j];
#pragma unroll
    for (int c = 0; c < 4; ++c) {
        float xc[16];
#pragma unroll
        for (int q = 0; q < 4; ++q) {
            f4 t = *reinterpret_cast<const f4*>(&xrow[c * 16 + 4 * q]);
            xc[4 * q] = t.x; xc[4 * q + 1] = t.y; xc[4 * q + 2] = t.z; xc[4 * q + 3] = t.w;
        }
#pragma unroll
        for (int i = 0; i < 16; ++i) {
            const float* row = &Wq[(c * 16 + i) * 16];   // 64 B contiguous, wave-uniform
#pragma unroll
            for (int j = 0; j < 16; ++j) acc[j] += row[j] * xc[i];
        }
    }
}

__global__ void __launch_bounds__(256) k_mlp(
    const float* __restrict__ hin,           // sliced layout [8][NN][8]
    const float* __restrict__ Wt, const float* __restrict__ Wt5,
    const float* __restrict__ b1, const float* __restrict__ b2,
    const float* __restrict__ b3, const float* __restrict__ b4,
    const float* __restrict__ b5,
    float* __restrict__ out) {
    __shared__ float xs[64 * MSTR];
    int lane = threadIdx.x & 63;
    int w = __builtin_amdgcn_readfirstlane(threadIdx.x >> 6);
    int nodeBase = blockIdx.x * 64;
    int node = nodeBase + lane;
    int o0 = w * 16;
    const float* xrow = &xs[lane * MSTR];

    // cooperative load from sliced layout: v = g*128 + nl*2 + half
#pragma unroll
    for (int i = 0; i < 4; ++i) {
        int v = threadIdx.x + 256 * i;
        int g = v >> 7;
        int r = v & 127;
        int nl = r >> 1;
        int half = v & 1;
        f4 t4 = make_float4(0.f, 0.f, 0.f, 0.f);
        int nd = nodeBase + nl;
        if (nd < NN)
            t4 = reinterpret_cast<const f4*>(hin)[(size_t)g * SL4 + nd * 2 + half];
        *reinterpret_cast<f4*>(&xs[nl * MSTR + g * 8 + half * 4]) = t4;
    }
    __syncthreads();

    float acc[16];
#define MLP_LAYER(L, Bp)                                                         \
    mlayer(Wt + ((L) * 4 + w) * 1024, Bp, o0, xrow, acc);                        \
    __syncthreads();                                                             \
    _Pragma("unroll")                                                            \
    for (int j = 0; j < 16; j += 4)                                              \
        *reinterpret_cast<f4*>(&xs[lane * MSTR + o0 + j]) =                      \
            make_float4(fmaxf(acc[j], 0.f), fmaxf(acc[j + 1], 0.f),              \
                        fmaxf(acc[j + 2], 0.f), fmaxf(acc[j + 3], 0.f));         \
    __syncthreads();

    MLP_LAYER(0, b1)
    MLP_LAYER(1, b2)
    MLP_LAYER(2, b3)
    MLP_LAYER(3, b4)
#undef MLP_LAYER

    int ocnt = (w == 3) ? 2 : 3;
    int ob = w * 3;
    float a5[3];
#pragma unroll
    for (int j = 0; j < 3; ++j) a5[j] = (j < ocnt) ? b5[ob + j] : 0.f;
#pragma unroll
    for (int c = 0; c < 4; ++c) {
        float xc[16];
#pragma unroll
        for (int q = 0; q < 4; ++q) {
            f4 t = *reinterpret_cast<const f4*>(&xrow[c * 16 + 4 * q]);
            xc[4 * q] = t.x; xc[4 * q + 1] = t.y; xc[4 * q + 2] = t.z; xc[4 * q + 3] = t.w;
        }
#pragma unroll
        for (int i = 0; i < 16; ++i) {
            const float* row = &Wt5[(c * 16 + i) * 16 + 4 * w];
#pragma unroll
            for (int j = 0; j < 3; ++j) a5[j] += row[j] * xc[i];
        }
    }
    if (node < NN) {
        for (int j = 0; j < ocnt; ++j) out[(size_t)node * 11 + ob + j] = a5[j];
    }
}

// ---------------- launch ----------------
extern "C" void kernel_launch(void* const* d_in, const int* in_sizes, int n_in,
                              void* d_out, int out_size, void* d_ws, size_t ws_size,
                              hipStream_t stream) {
    const float* h   = (const float*)d_in[0];
    const int*   ei  = (const int*)d_in[1];
    const float* gam = (const float*)d_in[2];
    const float* bet = (const float*)d_in[3];
    const float* W1  = (const float*)d_in[4];
    const float* as1 = (const float*)d_in[5];
    const float* ad1 = (const float*)d_in[6];
    const float* b1  = (const float*)d_in[7];
    const float* W2  = (const float*)d_in[8];
    const float* as2 = (const float*)d_in[9];
    const float* ad2 = (const float*)d_in[10];
    const float* b2  = (const float*)d_in[11];
    const float* fw1 = (const float*)d_in[12];
    const float* fb1 = (const float*)d_in[13];
    const float* fw2 = (const float*)d_in[14];
    const float* fb2 = (const float*)d_in[15];
    const float* fw3 = (const float*)d_in[16];
    const float* fb3 = (const float*)d_in[17];
    const float* fw4 = (const float*)d_in[18];
    const float* fb4 = (const float*)d_in[19];
    const float* fw5 = (const float*)d_in[20];
    const float* fb5 = (const float*)d_in[21];
    float* out = (float*)d_out;

    char* ws = (char*)d_ws;
    size_t off = 0;
    auto alloc = [&](size_t bytes) -> char* {
        char* p = ws + off;
        off += (bytes + 255) & ~(size_t)255;
        return p;
    };
    float* stats  = (float*)alloc(4 * sizeof(float));
    float* coef   = (float*)alloc(8 * sizeof(float));
    int*   H      = (int*)alloc((size_t)NBUCK * NBLK * sizeof(int));
    int*   boff   = (int*)alloc((size_t)(NBUCK + 1) * sizeof(int));
    int*   rowptr = (int*)alloc((size_t)(NN + 1) * sizeof(int));
    int*   srcl   = (int*)alloc((size_t)ET * sizeof(int));
    float* es     = (float*)alloc((size_t)NN * 2 * sizeof(float));
    float* ed     = (float*)alloc((size_t)NN * 2 * sizeof(float));
    float* Wt     = (float*)alloc((size_t)4 * 4 * 64 * 16 * sizeof(float));
    float* Wt5    = (float*)alloc((size_t)64 * 16 * sizeof(float));
    float* bufA   = (float*)alloc((size_t)NN * 64 * sizeof(float));
    float* bufB   = (float*)alloc((size_t)NN * 64 * sizeof(float));
    // aliases (dead before their hosts are written):
    unsigned* pairs = (unsigned*)bufA;                    // dead after k_bucket
    f4*     agg1a = (f4*)bufB;                            // dead after k_xform2f
    float2* agg1s = (float2*)(bufB + (size_t)NN * 4);
    f4*     nd1   = (f4*)(bufB + (size_t)NN * 6);
    float2* ed1   = (float2*)(bufB + (size_t)NN * 10);
    (void)ws_size; (void)in_sizes; (void)n_in; (void)out_size;

    k_init<<<1, 64, 0, stream>>>(stats);
    k_bnstats<<<256, 256, 0, stream>>>(h, stats);
    k_coef<<<1, 64, 0, stream>>>(W1, as1, ad1, coef);
    k_wprep<<<64, 256, 0, stream>>>(fw1, fw2, fw3, fw4, fw5, Wt, Wt5);

    // CSR build
    k_hist<<<NBLK, 256, 0, stream>>>(ei, H);
    k_bscan1<<<1, 1024, 0, stream>>>(H, boff);
    k_bscan2<<<NBUCK, 64, 0, stream>>>(H, boff);
    k_part<<<NBLK, 256, 0, stream>>>(ei, H, pairs);
    k_bucket<<<NBUCK, 1024, 0, stream>>>(pairs, boff, rowptr, srcl);

    // GAT layer 1 (rank-2 path)
    k_prep1<<<(NN + 255) / 256, 256, 0, stream>>>(h, stats, gam, bet, coef, nd1, ed1);
    k_gat1<<<(NN + 255) / 256, 256, 0, stream>>>(nd1, ed1, rowptr, srcl, agg1a, agg1s);

    // layer-1 finalize + layer-2 transform (writes sliced xps=bufA, per-head es/ed)
    k_xform2f<<<(NN + 255) / 256, 256, 0, stream>>>(agg1a, agg1s, W1, b1, W2, as2, ad2,
                                                    bufA, es, ed);
    // GAT layer 2: channel-sliced, XCD-affine
    k_gat2<<<3125 * 8, 256, 0, stream>>>(bufA, es, ed, rowptr, srcl, b2, bufB);

    // MLP head (sliced input)
    k_mlp<<<(NN + 63) / 64, 256, 0, stream>>>(bufB, Wt, Wt5, fb1, fb2, fb3, fb4, fb5, out);
}

// Round 8
// 353.199 us; speedup vs baseline: 1.3084x; 1.3084x over previous
//
#include <hip/hip_runtime.h>
#include <math.h>

#define NN 100000
#define EE 1600000
#define ET (EE + NN)          // edges + self loops = 1,700,000
#define NEG 0.2f
#define MSTR 68               // k_mlp LDS row stride (floats)
#define SMASK 0x1FFFF         // low 17 bits of packed srcl = src id

// CSR-build geometry
#define NBUCK 98              // ceil(NN/1024) buckets of 1024 dst nodes
#define NBLK 416              // ceil(ET/4096) partition blocks
#define BITEMS 4096           // items per partition block (256 thr x 16)
#define BCAP 20480            // fixed bucket capacity (mean 17351, sigma~132 -> ~24 sigma margin)

typedef float4 f4;

// ---------------- init: stats=0, gcnt=0 ----------------
__global__ void k_init(float* stats, int* gcnt) {
    int i = threadIdx.x;
    if (i < 4) stats[i] = 0.f;
    if (i < NBUCK) gcnt[i] = 0;
}

// ---------------- BN statistics ----------------
__global__ void k_bnstats(const float* __restrict__ h, float* stats) {
    int gid = blockIdx.x * blockDim.x + threadIdx.x;
    int stride = gridDim.x * blockDim.x;
    float s0 = 0.f, s1 = 0.f, q0 = 0.f, q1 = 0.f;
    for (int i = gid; i < NN; i += stride) {
        float2 v = reinterpret_cast<const float2*>(h)[i];
        s0 += v.x; q0 += v.x * v.x;
        s1 += v.y; q1 += v.y * v.y;
    }
#pragma unroll
    for (int off = 32; off >= 1; off >>= 1) {
        s0 += __shfl_xor(s0, off);
        s1 += __shfl_xor(s1, off);
        q0 += __shfl_xor(q0, off);
        q1 += __shfl_xor(q1, off);
    }
    if ((threadIdx.x & 63) == 0) {
        atomicAdd(&stats[0], s0); atomicAdd(&stats[1], s1);
        atomicAdd(&stats[2], q0); atomicAdd(&stats[3], q1);
    }
}

// ---------------- layer-1 rank-2 attention coefficients (8 floats) ----------------
__global__ void k_coef(const float* __restrict__ W1, const float* __restrict__ as1,
                       const float* __restrict__ ad1, float* __restrict__ coef) {
    int t = threadIdx.x;
    if (t >= 8) return;
    int sd = t >> 2, hh = (t >> 1) & 1, i = t & 1;
    const float* a = sd ? ad1 : as1;
    float s = 0.f;
    for (int c = 0; c < 32; ++c) s += W1[(hh * 32 + c) * 2 + i] * a[hh * 32 + c];
    coef[t] = s;
}

// ---------------- pack MLP weights (fw1..fw4 + fw5) for wave-uniform s_load streams ----------------
__global__ void k_wprep(const float* __restrict__ w1, const float* __restrict__ w2,
                        const float* __restrict__ w3, const float* __restrict__ w4,
                        const float* __restrict__ w5,
                        float* __restrict__ Wt, float* __restrict__ Wt5) {
    int idx = blockIdx.x * blockDim.x + threadIdx.x;
    if (idx < 4 * 4096) {
        int L = idx >> 12;
        int r = idx & 4095;
        int q = r >> 10;
        int t = r & 1023;
        int i = t >> 4, j = t & 15;
        const float* W = (L == 0) ? w1 : (L == 1) ? w2 : (L == 2) ? w3 : w4;
        Wt[idx] = W[(q * 16 + j) * 64 + i];
    }
    if (idx < 1024) {
        int i = idx >> 4, c = idx & 15;
        int w = c >> 2, j = c & 3;
        int o = 3 * w + j;
        int ocnt = (w == 3) ? 2 : 3;
        Wt5[idx] = (j < ocnt) ? w5[o * 64 + i] : 0.f;
    }
}

// ---------------- fused CSR partition: LDS hist + atomic run reservation + scatter ----------------
__global__ void __launch_bounds__(256) k_fpart(const int* __restrict__ ei, int* gcnt,
                                               unsigned* __restrict__ pairs) {
    __shared__ int hist[NBUCK];
    __shared__ int cur[NBUCK];
    int tid = threadIdx.x, blk = blockIdx.x;
    if (tid < NBUCK) hist[tid] = 0;
    int ss[16], dd[16];
    int base = blk * BITEMS;
    __syncthreads();
#pragma unroll
    for (int it = 0; it < 16; ++it) {
        int i = base + it * 256 + tid;
        int s = 0, d = -1;
        if (i < ET) {
            if (i < EE) { s = ei[i]; d = ei[EE + i]; }
            else { s = d = i - EE; }
            atomicAdd(&hist[d >> 10], 1);
        }
        ss[it] = s; dd[it] = d;
    }
    __syncthreads();
    if (tid < NBUCK) cur[tid] = tid * BCAP + atomicAdd(&gcnt[tid], hist[tid]);
    __syncthreads();
#pragma unroll
    for (int it = 0; it < 16; ++it) {
        int d = dd[it];
        if (d >= 0) {
            int pos = atomicAdd(&cur[d >> 10], 1);
            pairs[pos] = (unsigned)ss[it] | ((unsigned)(d & 1023) << 17);
        }
    }
}

// ---------------- 98-entry exclusive scan -> real bucket offsets ----------------
__global__ void k_scan98(const int* __restrict__ gcnt, int* __restrict__ rboff) {
    __shared__ int sm[128];
    int tid = threadIdx.x;
    int v = (tid < NBUCK) ? gcnt[tid] : 0;
    sm[tid] = v;
    __syncthreads();
    for (int off = 1; off < 128; off <<= 1) {
        int t = (tid >= off) ? sm[tid - off] : 0;
        __syncthreads();
        sm[tid] += t;
        __syncthreads();
    }
    if (tid < NBUCK) rboff[tid] = sm[tid] - v;
    if (tid == 0) rboff[NBUCK] = ET;
}

// ---------------- per-bucket local CSR (rowptr + packed srcl incl dloc) ----------------
__global__ void __launch_bounds__(1024) k_bucket(const unsigned* __restrict__ pairs,
                                                 const int* __restrict__ gcnt,
                                                 const int* __restrict__ rboff,
                                                 int* __restrict__ rowptr,
                                                 unsigned* __restrict__ srcl) {
    __shared__ int sh[1024];
    __shared__ int se[1024];
    int b = blockIdx.x, tid = threadIdx.x;
    int cnt = gcnt[b];
    int ibase = b * BCAP;
    int obase = rboff[b];
    sh[tid] = 0;
    __syncthreads();
    for (int k = tid; k < cnt; k += 1024) atomicAdd(&sh[pairs[ibase + k] >> 17], 1);
    __syncthreads();
    int deg = sh[tid];
    se[tid] = deg;
    __syncthreads();
    for (int off = 1; off < 1024; off <<= 1) {
        int t = (tid >= off) ? se[tid - off] : 0;
        __syncthreads();
        se[tid] += t;
        __syncthreads();
    }
    int excl = se[tid] - deg;
    int node = (b << 10) + tid;
    if (node < NN) rowptr[node] = obase + excl;
    sh[tid] = obase + excl;     // cursor
    __syncthreads();
    for (int k = tid; k < cnt; k += 1024) {
        unsigned p = pairs[ibase + k];
        int pos = atomicAdd(&sh[p >> 17], 1);
        srcl[pos] = p;          // keep dloc packed for k_ew
    }
    if (b == 0 && tid == 0) rowptr[NN] = ET;
}

// ---------------- layer-1 prep: BN apply + rank-2 attention scalars ----------------
__global__ void k_prep1(const float* __restrict__ h, const float* __restrict__ stats,
                        const float* __restrict__ gamma, const float* __restrict__ beta,
                        const float* __restrict__ coef,
                        f4* __restrict__ nd1, float2* __restrict__ ed1) {
    int n = blockIdx.x * blockDim.x + threadIdx.x;
    if (n >= NN) return;
    const float inv = 1.f / (float)NN;
    float mu0 = stats[0] * inv, mu1 = stats[1] * inv;
    float v0 = stats[2] * inv - mu0 * mu0;
    float v1 = stats[3] * inv - mu1 * mu1;
    float g0 = rsqrtf(v0 + 1e-5f) * gamma[0];
    float g1 = rsqrtf(v1 + 1e-5f) * gamma[1];
    float2 hv = reinterpret_cast<const float2*>(h)[n];
    float x0 = (hv.x - mu0) * g0 + beta[0];
    float x1 = (hv.y - mu1) * g1 + beta[1];
    nd1[n] = make_float4(x0 * coef[0] + x1 * coef[1], x0 * coef[2] + x1 * coef[3], x0, x1);
    ed1[n] = make_float2(x0 * coef[4] + x1 * coef[5], x0 * coef[6] + x1 * coef[7]);
}

// ---------------- layer-1 GAT: thread per dst, 16B gather (L2-resident 1.6MB) ----------------
__global__ void __launch_bounds__(256) k_gat1(
    const f4* __restrict__ nd1, const float2* __restrict__ ed1,
    const int* __restrict__ rowptr, const unsigned* __restrict__ srcl,
    f4* __restrict__ agg1a, float2* __restrict__ agg1s) {
    int n = blockIdx.x * blockDim.x + threadIdx.x;
    if (n >= NN) return;
    int beg = rowptr[n], end = rowptr[n + 1];
    float2 ed = ed1[n];
    float A0 = 0.f, B0 = 0.f, S0 = 0.f, A1 = 0.f, B1 = 0.f, S1 = 0.f;
    for (int k = beg; k < end; ++k) {
        int s = (int)(srcl[k] & SMASK);
        f4 p = nd1[s];
        float e0 = p.x + ed.x;
        float e1 = p.y + ed.y;
        e0 = (e0 > 0.f) ? e0 : NEG * e0;
        e1 = (e1 > 0.f) ? e1 : NEG * e1;
        float w0 = __expf(e0);
        float w1 = __expf(e1);
        A0 += w0 * p.z; B0 += w0 * p.w; S0 += w0;
        A1 += w1 * p.z; B1 += w1 * p.w; S1 += w1;
    }
    agg1a[n] = make_float4(A0, B0, A1, B1);
    agg1s[n] = make_float2(S0, S1);
}

// ---------------- layer-1 finalize + linear(64->64) + layer-2 attention scalars ----------------
// (round-5 numerics: es/ed computed from the actual xp dot products)
__global__ void k_xform2f(const f4* __restrict__ agg1a, const float2* __restrict__ agg1s,
                          const float* __restrict__ W1, const float* __restrict__ b1,
                          const float* __restrict__ W, const float* __restrict__ a_s,
                          const float* __restrict__ a_d,
                          float* __restrict__ xp, float2* __restrict__ es2v,
                          float2* __restrict__ ed2v) {
    int n = blockIdx.x * blockDim.x + threadIdx.x;
    if (n >= NN) return;
    f4 ag = agg1a[n];
    float2 sg = agg1s[n];
    float r0 = 1.f / (sg.x + 1e-16f);
    float r1 = 1.f / (sg.y + 1e-16f);
    float x[64];
#pragma unroll
    for (int f = 0; f < 64; ++f) {
        float A = (f < 32) ? ag.x : ag.z;
        float B = (f < 32) ? ag.y : ag.w;
        float r = (f < 32) ? r0 : r1;
        x[f] = fmaxf((A * W1[2 * f] + B * W1[2 * f + 1]) * r + b1[f], 0.f);
    }
    float es0 = 0.f, es1 = 0.f, ed0 = 0.f, ed1 = 0.f;
    f4* xo = reinterpret_cast<f4*>(xp + (size_t)n * 64);
#pragma unroll 1
    for (int fq = 0; fq < 16; ++fq) {
        float vq[4];
#pragma unroll
        for (int j = 0; j < 4; ++j) {
            int f = 4 * fq + j;
            float acc = 0.f;
#pragma unroll
            for (int i = 0; i < 64; ++i) acc += W[f * 64 + i] * x[i];
            vq[j] = acc;
            float ts = acc * a_s[f], td = acc * a_d[f];
            if (fq < 8) { es0 += ts; ed0 += td; } else { es1 += ts; ed1 += td; }
        }
        xo[fq] = make_float4(vq[0], vq[1], vq[2], vq[3]);
    }
    es2v[n] = make_float2(es0, es1);
    ed2v[n] = make_float2(ed0, ed1);
}

// ---------------- layer-2 edge weights: thread per edge, per-bucket blocks ----------------
__global__ void __launch_bounds__(1024) k_ew(const unsigned* __restrict__ srcl,
                                             const int* __restrict__ rboff,
                                             const float2* __restrict__ es2v,
                                             const float2* __restrict__ ed2v,
                                             float2* __restrict__ we) {
    int b = blockIdx.x;
    int beg = rboff[b], end = rboff[b + 1];
    for (int k = beg + threadIdx.x; k < end; k += 1024) {
        unsigned p = srcl[k];
        int s = (int)(p & SMASK);
        int d = (b << 10) + (int)(p >> 17);
        float2 es = es2v[s];
        float2 ed = ed2v[d];
        float e0 = es.x + ed.x, e1 = es.y + ed.y;
        e0 = (e0 > 0.f) ? e0 : NEG * e0;
        e1 = (e1 > 0.f) ? e1 : NEG * e1;
        we[k] = make_float2(__expf(e0), __expf(e1));
    }
}

// ---------------- layer-2 GAT (precomputed weights): wave per dst, pure gather+fma ----------------
__global__ void __launch_bounds__(256) k_gat2w(
    const float* __restrict__ xp, const float2* __restrict__ we,
    const int* __restrict__ rowptr, const unsigned* __restrict__ srcl,
    const float* __restrict__ bias, float* __restrict__ y) {
    int wid = (blockIdx.x * blockDim.x + threadIdx.x) >> 6;
    int lane = threadIdx.x & 63;
    if (wid >= NN) return;
    bool hi = lane >= 32;
    int beg = rowptr[wid], end = rowptr[wid + 1];
    float sum = 0.f, acc = 0.f;
    int k = beg;
    for (; k + 4 <= end; k += 4) {
        unsigned q0 = __builtin_nontemporal_load(&srcl[k]);
        unsigned q1 = __builtin_nontemporal_load(&srcl[k + 1]);
        unsigned q2 = __builtin_nontemporal_load(&srcl[k + 2]);
        unsigned q3 = __builtin_nontemporal_load(&srcl[k + 3]);
        float2 p0 = we[k], p1 = we[k + 1], p2 = we[k + 2], p3 = we[k + 3];
        float xa = xp[(size_t)(q0 & SMASK) * 64 + lane];
        float xb = xp[(size_t)(q1 & SMASK) * 64 + lane];
        float xc = xp[(size_t)(q2 & SMASK) * 64 + lane];
        float xd = xp[(size_t)(q3 & SMASK) * 64 + lane];
        float w0 = hi ? p0.y : p0.x;
        float w1 = hi ? p1.y : p1.x;
        float w2 = hi ? p2.y : p2.x;
        float w3 = hi ? p3.y : p3.x;
        sum += (w0 + w1) + (w2 + w3);
        acc += (w0 * xa + w1 * xb) + (w2 * xc + w3 * xd);
    }
    for (; k < end; ++k) {
        unsigned q = __builtin_nontemporal_load(&srcl[k]);
        float2 p = we[k];
        float w = hi ? p.y : p.x;
        sum += w;
        acc += w * xp[(size_t)(q & SMASK) * 64 + lane];
    }
    float r = acc / (sum + 1e-16f) + bias[lane];
    y[(size_t)wid * 64 + lane] = fmaxf(r, 0.f);               // post-GAT ReLU
}

// ---------------- layer-2 GAT fallback (fused exp, if ws too small for we) ----------------
__global__ void __launch_bounds__(256) k_gat2f(
    const float* __restrict__ xp, const float2* __restrict__ es2v, const float2* __restrict__ ed2v,
    const int* __restrict__ rowptr, const unsigned* __restrict__ srcl,
    const float* __restrict__ bias, float* __restrict__ y) {
    int wid = (blockIdx.x * blockDim.x + threadIdx.x) >> 6;
    int lane = threadIdx.x & 63;
    if (wid >= NN) return;
    bool hi = lane >= 32;
    int beg = rowptr[wid], end = rowptr[wid + 1];
    float2 edp = ed2v[wid];
    float edv = hi ? edp.y : edp.x;
    float sum = 0.f, acc = 0.f;
    for (int k = beg; k < end; ++k) {
        int s = (int)(srcl[k] & SMASK);
        float2 esp = es2v[s];
        float e = (hi ? esp.y : esp.x) + edv;
        e = (e > 0.f) ? e : NEG * e;
        float w = __expf(e);
        sum += w;
        acc += w * xp[(size_t)s * 64 + lane];
    }
    float r = acc / (sum + 1e-16f) + bias[lane];
    y[(size_t)wid * 64 + lane] = fmaxf(r, 0.f);
}

// ---------------- fused 5-layer MLP: 4 waves/block, wave w owns outputs [16w,16w+16) ----------------
__device__ __forceinline__ void mlayer(const float* __restrict__ Wq, const float* __restrict__ B,
                                       int o0, const float* __restrict__ xrow, float* acc) {
#pragma unroll
    for (int j = 0; j < 16; ++j) acc[j] = B[o0 + j];
#pragma unroll
    for (int c = 0; c < 4; ++c) {
        float xc[16];
#pragma unroll
        for (int q = 0; q < 4; ++q) {
            f4 t = *reinterpret_cast<const f4*>(&xrow[c * 16 + 4 * q]);
            xc[4 * q] = t.x; xc[4 * q + 1] = t.y; xc[4 * q + 2] = t.z; xc[4 * q + 3] = t.w;
        }
#pragma unroll
        for (int i = 0; i < 16; ++i) {
            const float* row = &Wq[(c * 16 + i) * 16];   // 64 B contiguous, wave-uniform
#pragma unroll
            for (int j = 0; j < 16; ++j) acc[j] += row[j] * xc[i];
        }
    }
}

__global__ void __launch_bounds__(256) k_mlp(
    const float* __restrict__ hin,
    const float* __restrict__ Wt, const float* __restrict__ Wt5,
    const float* __restrict__ b1, const float* __restrict__ b2,
    const float* __restrict__ b3, const float* __restrict__ b4,
    const float* __restrict__ b5,
    float* __restrict__ out) {
    __shared__ float xs[64 * MSTR];
    int lane = threadIdx.x & 63;
    int w = __builtin_amdgcn_readfirstlane(threadIdx.x >> 6);
    int nodeBase = blockIdx.x * 64;
    int node = nodeBase + lane;
    int o0 = w * 16;
    const float* xrow = &xs[lane * MSTR];

#pragma unroll
    for (int i = 0; i < 4; ++i) {
        int v = threadIdx.x + 256 * i;
        int nl = v >> 4;
        int f = (v & 15) << 2;
        f4 t4 = make_float4(0.f, 0.f, 0.f, 0.f);
        if (nodeBase + nl < NN)
            t4 = reinterpret_cast<const f4*>(hin)[(size_t)(nodeBase + nl) * 16 + (v & 15)];
        *reinterpret_cast<f4*>(&xs[nl * MSTR + f]) = t4;
    }
    __syncthreads();

    float acc[16];
#define MLP_LAYER(L, Bp)                                                         \
    mlayer(Wt + ((L) * 4 + w) * 1024, Bp, o0, xrow, acc);                        \
    __syncthreads();                                                             \
    _Pragma("unroll")                                                            \
    for (int j = 0; j < 16; j += 4)                                              \
        *reinterpret_cast<f4*>(&xs[lane * MSTR + o0 + j]) =                      \
            make_float4(fmaxf(acc[j], 0.f), fmaxf(acc[j + 1], 0.f),              \
                        fmaxf(acc[j + 2], 0.f), fmaxf(acc[j + 3], 0.f));         \
    __syncthreads();

    MLP_LAYER(0, b1)
    MLP_LAYER(1, b2)
    MLP_LAYER(2, b3)
    MLP_LAYER(3, b4)
#undef MLP_LAYER

    int ocnt = (w == 3) ? 2 : 3;
    int ob = w * 3;
    float a5[3];
#pragma unroll
    for (int j = 0; j < 3; ++j) a5[j] = (j < ocnt) ? b5[ob + j] : 0.f;
#pragma unroll
    for (int c = 0; c < 4; ++c) {
        float xc[16];
#pragma unroll
        for (int q = 0; q < 4; ++q) {
            f4 t = *reinterpret_cast<const f4*>(&xrow[c * 16 + 4 * q]);
            xc[4 * q] = t.x; xc[4 * q + 1] = t.y; xc[4 * q + 2] = t.z; xc[4 * q + 3] = t.w;
        }
#pragma unroll
        for (int i = 0; i < 16; ++i) {
            const float* row = &Wt5[(c * 16 + i) * 16 + 4 * w];
#pragma unroll
            for (int j = 0; j < 3; ++j) a5[j] += row[j] * xc[i];
        }
    }
    if (node < NN) {
        for (int j = 0; j < ocnt; ++j) out[(size_t)node * 11 + ob + j] = a5[j];
    }
}

// ---------------- launch ----------------
extern "C" void kernel_launch(void* const* d_in, const int* in_sizes, int n_in,
                              void* d_out, int out_size, void* d_ws, size_t ws_size,
                              hipStream_t stream) {
    const float* h   = (const float*)d_in[0];
    const int*   ei  = (const int*)d_in[1];
    const float* gam = (const float*)d_in[2];
    const float* bet = (const float*)d_in[3];
    const float* W1  = (const float*)d_in[4];
    const float* as1 = (const float*)d_in[5];
    const float* ad1 = (const float*)d_in[6];
    const float* b1  = (const float*)d_in[7];
    const float* W2  = (const float*)d_in[8];
    const float* as2 = (const float*)d_in[9];
    const float* ad2 = (const float*)d_in[10];
    const float* b2  = (const float*)d_in[11];
    const float* fw1 = (const float*)d_in[12];
    const float* fb1 = (const float*)d_in[13];
    const float* fw2 = (const float*)d_in[14];
    const float* fb2 = (const float*)d_in[15];
    const float* fw3 = (const float*)d_in[16];
    const float* fb3 = (const float*)d_in[17];
    const float* fw4 = (const float*)d_in[18];
    const float* fb4 = (const float*)d_in[19];
    const float* fw5 = (const float*)d_in[20];
    const float* fb5 = (const float*)d_in[21];
    float* out = (float*)d_out;

    char* ws = (char*)d_ws;
    size_t off = 0;
    auto alloc = [&](size_t bytes) -> char* {
        char* p = ws + off;
        off += (bytes + 255) & ~(size_t)255;
        return p;
    };
    float* stats  = (float*)alloc(4 * sizeof(float));
    float* coef   = (float*)alloc(8 * sizeof(float));
    int*   gcnt   = (int*)alloc(NBUCK * sizeof(int));
    int*   rboff  = (int*)alloc((NBUCK + 1) * sizeof(int));
    int*   rowptr = (int*)alloc((size_t)(NN + 1) * sizeof(int));
    unsigned* srcl = (unsigned*)alloc((size_t)ET * sizeof(unsigned));
    float2* es2v  = (float2*)alloc((size_t)NN * sizeof(float2));
    float2* ed2v  = (float2*)alloc((size_t)NN * sizeof(float2));
    float* Wt     = (float*)alloc((size_t)4 * 4096 * sizeof(float));
    float* Wt5    = (float*)alloc((size_t)1024 * sizeof(float));
    float* bufA   = (float*)alloc((size_t)NN * 64 * sizeof(float));   // xp rows
    float* bufB   = (float*)alloc((size_t)NN * 64 * sizeof(float));   // y rows (+early aliases)
    // aliases (dead before their hosts are written):
    unsigned* pairs = (unsigned*)bufA;                          // 98*20480 u32 = 8MB; dead after k_bucket
    f4*     agg1a = (f4*)bufB;                                  // floats [0 .. 400000)
    float2* agg1s = (float2*)(bufB + 400000);                   // [400000 .. 600000)
    f4*     nd1   = (f4*)(bufB + 600000);                       // [600000 .. 1000000)
    float2* ed1   = (float2*)(bufB + 1000000);                  // [1000000 .. 1200000)
    // optional edge-weight buffer (13.6MB) if workspace permits
    float2* we = nullptr;
    if (ws_size >= off + (size_t)ET * sizeof(float2) + 256)
        we = (float2*)alloc((size_t)ET * sizeof(float2));
    (void)in_sizes; (void)n_in; (void)out_size;

    k_init<<<1, 128, 0, stream>>>(stats, gcnt);
    k_bnstats<<<256, 256, 0, stream>>>(h, stats);
    k_coef<<<1, 64, 0, stream>>>(W1, as1, ad1, coef);
    k_wprep<<<64, 256, 0, stream>>>(fw1, fw2, fw3, fw4, fw5, Wt, Wt5);

    // fused CSR build
    k_fpart<<<NBLK, 256, 0, stream>>>(ei, gcnt, pairs);
    k_scan98<<<1, 128, 0, stream>>>(gcnt, rboff);
    k_bucket<<<NBUCK, 1024, 0, stream>>>(pairs, gcnt, rboff, rowptr, srcl);

    // GAT layer 1 (rank-2 path)
    k_prep1<<<(NN + 255) / 256, 256, 0, stream>>>(h, stats, gam, bet, coef, nd1, ed1);
    k_gat1<<<(NN + 255) / 256, 256, 0, stream>>>(nd1, ed1, rowptr, srcl, agg1a, agg1s);

    // layer-1 finalize + layer-2 transform (round-5 numerics; writes xp=bufA, es2v, ed2v)
    k_xform2f<<<(NN + 255) / 256, 256, 0, stream>>>(agg1a, agg1s, W1, b1, W2, as2, ad2,
                                                    bufA, es2v, ed2v);

    // GAT layer 2
    if (we) {
        k_ew<<<NBUCK, 1024, 0, stream>>>(srcl, rboff, es2v, ed2v, we);
        k_gat2w<<<(NN * 64) / 256, 256, 0, stream>>>(bufA, we, rowptr, srcl, b2, bufB);
    } else {
        k_gat2f<<<(NN * 64) / 256, 256, 0, stream>>>(bufA, es2v, ed2v, rowptr, srcl, b2, bufB);
    }

    // MLP head
    k_mlp<<<(NN + 63) / 64, 256, 0, stream>>>(bufB, Wt, Wt5, fb1, fb2, fb3, fb4, fb5, out);
}

// Round 9
// 333.250 us; speedup vs baseline: 1.3867x; 1.0599x over previous
//
#include <hip/hip_runtime.h>
#include <math.h>

#define NN 100000
#define EE 1600000
#define ET (EE + NN)          // edges + self loops = 1,700,000
#define NEG 0.2f
#define MSTR 68               // k_mlp LDS row stride (floats)

// CSR-build geometry (round-3/5 proven path)
#define NBUCK 98              // ceil(NN/1024) buckets of 1024 dst nodes
#define NBLK 416              // ceil(ET/4096) partition blocks
#define BITEMS 4096           // items per partition block (256 thr x 16)

typedef float4 f4;

// ---------------- init: stats=0 ----------------
__global__ void k_init(float* stats) {
    int i = threadIdx.x;
    if (i < 4) stats[i] = 0.f;
}

// ---------------- BN statistics ----------------
__global__ void k_bnstats(const float* __restrict__ h, float* stats) {
    int gid = blockIdx.x * blockDim.x + threadIdx.x;
    int stride = gridDim.x * blockDim.x;
    float s0 = 0.f, s1 = 0.f, q0 = 0.f, q1 = 0.f;
    for (int i = gid; i < NN; i += stride) {
        float2 v = reinterpret_cast<const float2*>(h)[i];
        s0 += v.x; q0 += v.x * v.x;
        s1 += v.y; q1 += v.y * v.y;
    }
#pragma unroll
    for (int off = 32; off >= 1; off >>= 1) {
        s0 += __shfl_xor(s0, off);
        s1 += __shfl_xor(s1, off);
        q0 += __shfl_xor(q0, off);
        q1 += __shfl_xor(q1, off);
    }
    if ((threadIdx.x & 63) == 0) {
        atomicAdd(&stats[0], s0); atomicAdd(&stats[1], s1);
        atomicAdd(&stats[2], q0); atomicAdd(&stats[3], q1);
    }
}

// ---------------- layer-1 rank-2 attention coefficients ----------------
__global__ void k_coef(const float* __restrict__ W1, const float* __restrict__ as1,
                       const float* __restrict__ ad1, float* __restrict__ coef) {
    int t = threadIdx.x;
    if (t >= 8) return;
    int sd = t >> 2, hh = (t >> 1) & 1, i = t & 1;
    const float* a = sd ? ad1 : as1;
    float s = 0.f;
    for (int c = 0; c < 32; ++c) s += W1[(hh * 32 + c) * 2 + i] * a[hh * 32 + c];
    coef[t] = s;
}

// ---------------- pack MLP weights for wave-uniform contiguous s_load streams ----------------
__global__ void k_wprep(const float* __restrict__ w1, const float* __restrict__ w2,
                        const float* __restrict__ w3, const float* __restrict__ w4,
                        const float* __restrict__ w5,
                        float* __restrict__ Wt, float* __restrict__ Wt5) {
    int idx = blockIdx.x * blockDim.x + threadIdx.x;
    if (idx < 4 * 4096) {
        int L = idx >> 12;
        int r = idx & 4095;
        int q = r >> 10;
        int t = r & 1023;
        int i = t >> 4, j = t & 15;
        const float* W = (L == 0) ? w1 : (L == 1) ? w2 : (L == 2) ? w3 : w4;
        Wt[idx] = W[(q * 16 + j) * 64 + i];
    }
    if (idx < 1024) {
        int i = idx >> 4, c = idx & 15;
        int w = c >> 2, j = c & 3;
        int o = 3 * w + j;
        int ocnt = (w == 3) ? 2 : 3;
        Wt5[idx] = (j < ocnt) ? w5[o * 64 + i] : 0.f;
    }
}

// ---------------- CSR pass A: per-block bucket histogram ----------------
__global__ void __launch_bounds__(256) k_hist(const int* __restrict__ ei, int* __restrict__ H) {
    __shared__ int hist[NBUCK];
    int tid = threadIdx.x, blk = blockIdx.x;
    if (tid < NBUCK) hist[tid] = 0;
    __syncthreads();
    int base = blk * BITEMS;
#pragma unroll
    for (int it = 0; it < 16; ++it) {
        int i = base + it * 256 + tid;
        if (i < ET) {
            int d = (i < EE) ? ei[EE + i] : (i - EE);
            atomicAdd(&hist[d >> 10], 1);
        }
    }
    __syncthreads();
    if (tid < NBUCK) H[tid * NBLK + blk] = hist[tid];
}

// ---------------- CSR pass B1: bucket totals + base offsets (1 block) ----------------
__global__ void __launch_bounds__(1024) k_bscan1(const int* __restrict__ H, int* __restrict__ boff) {
    __shared__ int part[1024];
    __shared__ int btot[NBUCK];
    int tid = threadIdx.x;
    int b = tid >> 3, k = tid & 7;
    int s = 0;
    if (b < NBUCK)
        for (int blk = k; blk < NBLK; blk += 8) s += H[b * NBLK + blk];
    part[tid] = s;
    __syncthreads();
    if (tid < NBUCK) {
        int t = 0;
#pragma unroll
        for (int j = 0; j < 8; ++j) t += part[tid * 8 + j];
        btot[tid] = t;
    }
    __syncthreads();
    if (tid == 0) {
        int run = 0;
        for (int bb = 0; bb < NBUCK; ++bb) { boff[bb] = run; run += btot[bb]; }
        boff[NBUCK] = ET;
    }
}

// ---------------- CSR pass B2: per-(bucket,block) absolute offsets ----------------
__global__ void __launch_bounds__(64) k_bscan2(int* __restrict__ H, const int* __restrict__ boff) {
    int b = blockIdx.x, lane = threadIdx.x;
    int s = 0;
    int base_i = lane * 7;
#pragma unroll
    for (int j = 0; j < 7; ++j) {
        int idx = base_i + j;
        if (idx < NBLK) s += H[b * NBLK + idx];
    }
    int incl = s;
#pragma unroll
    for (int d = 1; d < 64; d <<= 1) {
        int n = __shfl_up(incl, d, 64);
        if (lane >= d) incl += n;
    }
    int run = boff[b] + incl - s;
#pragma unroll
    for (int j = 0; j < 7; ++j) {
        int idx = base_i + j;
        if (idx < NBLK) {
            int t = H[b * NBLK + idx];
            H[b * NBLK + idx] = run;
            run += t;
        }
    }
}

// ---------------- CSR pass C: partition edges into bucket regions ----------------
__global__ void __launch_bounds__(256) k_part(const int* __restrict__ ei, const int* __restrict__ H,
                                              unsigned* __restrict__ pairs) {
    __shared__ int cur[NBUCK];
    int tid = threadIdx.x, blk = blockIdx.x;
    if (tid < NBUCK) cur[tid] = H[tid * NBLK + blk];
    __syncthreads();
    int base = blk * BITEMS;
#pragma unroll
    for (int it = 0; it < 16; ++it) {
        int i = base + it * 256 + tid;
        if (i < ET) {
            int s, d;
            if (i < EE) { s = ei[i]; d = ei[EE + i]; }
            else { s = d = i - EE; }
            int b = d >> 10;
            int pos = atomicAdd(&cur[b], 1);
            pairs[pos] = (unsigned)s | ((unsigned)(d & 1023) << 17);
        }
    }
}

// ---------------- CSR pass D: per-bucket local CSR (rowptr + srcl) ----------------
__global__ void __launch_bounds__(1024) k_bucket(const unsigned* __restrict__ pairs,
                                                 const int* __restrict__ boff,
                                                 int* __restrict__ rowptr, int* __restrict__ srcl) {
    __shared__ int sh[1024];
    __shared__ int se[1024];
    int b = blockIdx.x, tid = threadIdx.x;
    int bb = boff[b], be = boff[b + 1];
    sh[tid] = 0;
    __syncthreads();
    for (int k = bb + tid; k < be; k += 1024) atomicAdd(&sh[pairs[k] >> 17], 1);
    __syncthreads();
    int deg = sh[tid];
    se[tid] = deg;
    __syncthreads();
    for (int off = 1; off < 1024; off <<= 1) {
        int t = (tid >= off) ? se[tid - off] : 0;
        __syncthreads();
        se[tid] += t;
        __syncthreads();
    }
    int excl = se[tid] - deg;
    int node = (b << 10) + tid;
    if (node < NN) rowptr[node] = bb + excl;
    sh[tid] = bb + excl;     // cursor
    __syncthreads();
    for (int k = bb + tid; k < be; k += 1024) {
        unsigned p = pairs[k];
        int pos = atomicAdd(&sh[p >> 17], 1);
        srcl[pos] = (int)(p & 0x1FFFFu);
    }
    if (b == 0 && tid == 0) rowptr[NN] = ET;
}

// ---------------- layer-1 prep: BN apply + rank-2 attention scalars ----------------
__global__ void k_prep1(const float* __restrict__ h, const float* __restrict__ stats,
                        const float* __restrict__ gamma, const float* __restrict__ beta,
                        const float* __restrict__ coef,
                        f4* __restrict__ nd1, float2* __restrict__ ed1) {
    int n = blockIdx.x * blockDim.x + threadIdx.x;
    if (n >= NN) return;
    const float inv = 1.f / (float)NN;
    float mu0 = stats[0] * inv, mu1 = stats[1] * inv;
    float v0 = stats[2] * inv - mu0 * mu0;
    float v1 = stats[3] * inv - mu1 * mu1;
    float g0 = rsqrtf(v0 + 1e-5f) * gamma[0];
    float g1 = rsqrtf(v1 + 1e-5f) * gamma[1];
    float2 hv = reinterpret_cast<const float2*>(h)[n];
    float x0 = (hv.x - mu0) * g0 + beta[0];
    float x1 = (hv.y - mu1) * g1 + beta[1];
    nd1[n] = make_float4(x0 * coef[0] + x1 * coef[1], x0 * coef[2] + x1 * coef[3], x0, x1);
    ed1[n] = make_float2(x0 * coef[4] + x1 * coef[5], x0 * coef[6] + x1 * coef[7]);
}

// ---------------- layer-1 GAT: thread per dst, 16B gather (L2-resident 1.6MB) ----------------
__global__ void __launch_bounds__(256) k_gat1(
    const f4* __restrict__ nd1, const float2* __restrict__ ed1,
    const int* __restrict__ rowptr, const int* __restrict__ srcl,
    f4* __restrict__ agg1a, float2* __restrict__ agg1s) {
    int n = blockIdx.x * blockDim.x + threadIdx.x;
    if (n >= NN) return;
    int beg = rowptr[n], end = rowptr[n + 1];
    float2 ed = ed1[n];
    float A0 = 0.f, B0 = 0.f, S0 = 0.f, A1 = 0.f, B1 = 0.f, S1 = 0.f;
    for (int k = beg; k < end; ++k) {
        int s = srcl[k];
        f4 p = nd1[s];
        float e0 = p.x + ed.x;
        float e1 = p.y + ed.y;
        e0 = (e0 > 0.f) ? e0 : NEG * e0;
        e1 = (e1 > 0.f) ? e1 : NEG * e1;
        float w0 = __expf(e0);
        float w1 = __expf(e1);
        A0 += w0 * p.z; B0 += w0 * p.w; S0 += w0;
        A1 += w1 * p.z; B1 += w1 * p.w; S1 += w1;
    }
    agg1a[n] = make_float4(A0, B0, A1, B1);
    agg1s[n] = make_float2(S0, S1);
}

// ---------------- layer-1 finalize + linear(64->64) + layer-2 attention scalars ----------------
__global__ void k_xform2f(const f4* __restrict__ agg1a, const float2* __restrict__ agg1s,
                          const float* __restrict__ W1, const float* __restrict__ b1,
                          const float* __restrict__ W, const float* __restrict__ a_s,
                          const float* __restrict__ a_d,
                          float* __restrict__ xp, float2* __restrict__ es2v,
                          float2* __restrict__ ed2v) {
    int n = blockIdx.x * blockDim.x + threadIdx.x;
    if (n >= NN) return;
    f4 ag = agg1a[n];
    float2 sg = agg1s[n];
    float r0 = 1.f / (sg.x + 1e-16f);
    float r1 = 1.f / (sg.y + 1e-16f);
    float x[64];
#pragma unroll
    for (int f = 0; f < 64; ++f) {
        float A = (f < 32) ? ag.x : ag.z;
        float B = (f < 32) ? ag.y : ag.w;
        float r = (f < 32) ? r0 : r1;
        x[f] = fmaxf((A * W1[2 * f] + B * W1[2 * f + 1]) * r + b1[f], 0.f);
    }
    float es0 = 0.f, es1 = 0.f, ed0 = 0.f, ed1 = 0.f;
    f4* xo = reinterpret_cast<f4*>(xp + (size_t)n * 64);
#pragma unroll 1
    for (int fq = 0; fq < 16; ++fq) {
        float vq[4];
#pragma unroll
        for (int j = 0; j < 4; ++j) {
            int f = 4 * fq + j;
            float acc = 0.f;
#pragma unroll
            for (int i = 0; i < 64; ++i) acc += W[f * 64 + i] * x[i];
            vq[j] = acc;
            float ts = acc * a_s[f], td = acc * a_d[f];
            if (fq < 8) { es0 += ts; ed0 += td; } else { es1 += ts; ed1 += td; }
        }
        xo[fq] = make_float4(vq[0], vq[1], vq[2], vq[3]);
    }
    es2v[n] = make_float2(es0, es1);
    ed2v[n] = make_float2(ed0, ed1);
}

// ---------------- layer-2 GAT: wave per dst, fused exp, 8-deep load pipeline ----------------
__global__ void __launch_bounds__(256) k_gat2(
    const float* __restrict__ xp, const float2* __restrict__ es2v, const float2* __restrict__ ed2v,
    const int* __restrict__ rowptr, const int* __restrict__ srcl,
    const float* __restrict__ bias, float* __restrict__ y) {
    int wid = (blockIdx.x * blockDim.x + threadIdx.x) >> 6;
    int lane = threadIdx.x & 63;
    if (wid >= NN) return;
    bool hi = lane >= 32;
    int beg = rowptr[wid], end = rowptr[wid + 1];
    float2 edp = ed2v[wid];
    float edv = hi ? edp.y : edp.x;
    float sum = 0.f, acc = 0.f;
    int k = beg;
    // 8-deep: batch all loads (srcl -> es2v/xp) before the exp/fma block
    for (; k + 8 <= end; k += 8) {
        int s[8];
#pragma unroll
        for (int j = 0; j < 8; ++j) s[j] = srcl[k + j];
        float2 esp[8];
        float xv[8];
#pragma unroll
        for (int j = 0; j < 8; ++j) {
            esp[j] = es2v[s[j]];
            xv[j] = xp[(size_t)s[j] * 64 + lane];
        }
#pragma unroll
        for (int j = 0; j < 8; ++j) {
            float e = (hi ? esp[j].y : esp[j].x) + edv;
            e = (e > 0.f) ? e : NEG * e;
            float w = __expf(e);
            sum += w;
            acc += w * xv[j];
        }
    }
    for (; k < end; ++k) {
        int s = srcl[k];
        float2 esp = es2v[s];
        float e = (hi ? esp.y : esp.x) + edv;
        e = (e > 0.f) ? e : NEG * e;
        float w = __expf(e);
        sum += w;
        acc += w * xp[(size_t)s * 64 + lane];
    }
    float r = acc / (sum + 1e-16f) + bias[lane];
    y[(size_t)wid * 64 + lane] = fmaxf(r, 0.f);               // post-GAT ReLU
}

// ---------------- fused 5-layer MLP: 4 waves/block, wave w owns outputs [16w,16w+16) ----------------
__device__ __forceinline__ void mlayer(const float* __restrict__ Wq, const float* __restrict__ B,
                                       int o0, const float* __restrict__ xrow, float* acc) {
#pragma unroll
    for (int j = 0; j < 16; ++j) acc[j] = B[o0 + j];
#pragma unroll
    for (int c = 0; c < 4; ++c) {
        float xc[16];
#pragma unroll
        for (int q = 0; q < 4; ++q) {
            f4 t = *reinterpret_cast<const f4*>(&xrow[c * 16 + 4 * q]);
            xc[4 * q] = t.x; xc[4 * q + 1] = t.y; xc[4 * q + 2] = t.z; xc[4 * q + 3] = t.w;
        }
#pragma unroll
        for (int i = 0; i < 16; ++i) {
            const float* row = &Wq[(c * 16 + i) * 16];   // 64 B contiguous, wave-uniform
#pragma unroll
            for (int j = 0; j < 16; ++j) acc[j] += row[j] * xc[i];
        }
    }
}

__global__ void __launch_bounds__(256) k_mlp(
    const float* __restrict__ hin,
    const float* __restrict__ Wt, const float* __restrict__ Wt5,
    const float* __restrict__ b1, const float* __restrict__ b2,
    const float* __restrict__ b3, const float* __restrict__ b4,
    const float* __restrict__ b5,
    float* __restrict__ out) {
    __shared__ float xs[64 * MSTR];
    int lane = threadIdx.x & 63;
    int w = __builtin_amdgcn_readfirstlane(threadIdx.x >> 6);
    int nodeBase = blockIdx.x * 64;
    int node = nodeBase + lane;
    int o0 = w * 16;
    const float* xrow = &xs[lane * MSTR];

#pragma unroll
    for (int i = 0; i < 4; ++i) {
        int v = threadIdx.x + 256 * i;
        int nl = v >> 4;
        int f = (v & 15) << 2;
        f4 t4 = make_float4(0.f, 0.f, 0.f, 0.f);
        if (nodeBase + nl < NN)
            t4 = reinterpret_cast<const f4*>(hin)[(size_t)(nodeBase + nl) * 16 + (v & 15)];
        *reinterpret_cast<f4*>(&xs[nl * MSTR + f]) = t4;
    }
    __syncthreads();

    float acc[16];
#define MLP_LAYER(L, Bp)                                                         \
    mlayer(Wt + ((L) * 4 + w) * 1024, Bp, o0, xrow, acc);                        \
    __syncthreads();                                                             \
    _Pragma("unroll")                                                            \
    for (int j = 0; j < 16; j += 4)                                              \
        *reinterpret_cast<f4*>(&xs[lane * MSTR + o0 + j]) =                      \
            make_float4(fmaxf(acc[j], 0.f), fmaxf(acc[j + 1], 0.f),              \
                        fmaxf(acc[j + 2], 0.f), fmaxf(acc[j + 3], 0.f));         \
    __syncthreads();

    MLP_LAYER(0, b1)
    MLP_LAYER(1, b2)
    MLP_LAYER(2, b3)
    MLP_LAYER(3, b4)
#undef MLP_LAYER

    int ocnt = (w == 3) ? 2 : 3;
    int ob = w * 3;
    float a5[3];
#pragma unroll
    for (int j = 0; j < 3; ++j) a5[j] = (j < ocnt) ? b5[ob + j] : 0.f;
#pragma unroll
    for (int c = 0; c < 4; ++c) {
        float xc[16];
#pragma unroll
        for (int q = 0; q < 4; ++q) {
            f4 t = *reinterpret_cast<const f4*>(&xrow[c * 16 + 4 * q]);
            xc[4 * q] = t.x; xc[4 * q + 1] = t.y; xc[4 * q + 2] = t.z; xc[4 * q + 3] = t.w;
        }
#pragma unroll
        for (int i = 0; i < 16; ++i) {
            const float* row = &Wt5[(c * 16 + i) * 16 + 4 * w];
#pragma unroll
            for (int j = 0; j < 3; ++j) a5[j] += row[j] * xc[i];
        }
    }
    if (node < NN) {
        for (int j = 0; j < ocnt; ++j) out[(size_t)node * 11 + ob + j] = a5[j];
    }
}

// ---------------- launch ----------------
extern "C" void kernel_launch(void* const* d_in, const int* in_sizes, int n_in,
                              void* d_out, int out_size, void* d_ws, size_t ws_size,
                              hipStream_t stream) {
    const float* h   = (const float*)d_in[0];
    const int*   ei  = (const int*)d_in[1];
    const float* gam = (const float*)d_in[2];
    const float* bet = (const float*)d_in[3];
    const float* W1  = (const float*)d_in[4];
    const float* as1 = (const float*)d_in[5];
    const float* ad1 = (const float*)d_in[6];
    const float* b1  = (const float*)d_in[7];
    const float* W2  = (const float*)d_in[8];
    const float* as2 = (const float*)d_in[9];
    const float* ad2 = (const float*)d_in[10];
    const float* b2  = (const float*)d_in[11];
    const float* fw1 = (const float*)d_in[12];
    const float* fb1 = (const float*)d_in[13];
    const float* fw2 = (const float*)d_in[14];
    const float* fb2 = (const float*)d_in[15];
    const float* fw3 = (const float*)d_in[16];
    const float* fb3 = (const float*)d_in[17];
    const float* fw4 = (const float*)d_in[18];
    const float* fb4 = (const float*)d_in[19];
    const float* fw5 = (const float*)d_in[20];
    const float* fb5 = (const float*)d_in[21];
    float* out = (float*)d_out;

    char* ws = (char*)d_ws;
    size_t off = 0;
    auto alloc = [&](size_t bytes) -> char* {
        char* p = ws + off;
        off += (bytes + 255) & ~(size_t)255;
        return p;
    };
    float* stats  = (float*)alloc(4 * sizeof(float));
    float* coef   = (float*)alloc(8 * sizeof(float));
    int*   H      = (int*)alloc((size_t)NBUCK * NBLK * sizeof(int));
    int*   boff   = (int*)alloc((size_t)(NBUCK + 1) * sizeof(int));
    int*   rowptr = (int*)alloc((size_t)(NN + 1) * sizeof(int));
    int*   srcl   = (int*)alloc((size_t)ET * sizeof(int));
    float2* es2v  = (float2*)alloc((size_t)NN * sizeof(float2));
    float2* ed2v  = (float2*)alloc((size_t)NN * sizeof(float2));
    float* Wt     = (float*)alloc((size_t)4 * 4096 * sizeof(float));
    float* Wt5    = (float*)alloc((size_t)1024 * sizeof(float));
    float* bufA   = (float*)alloc((size_t)NN * 64 * sizeof(float));
    float* bufB   = (float*)alloc((size_t)NN * 64 * sizeof(float));
    // aliases (dead before their hosts are written):
    unsigned* pairs = (unsigned*)bufA;                    // dead after k_bucket; bufA written by k_xform2f
    f4*     agg1a = (f4*)bufB;                            // floats [0 .. 400000)
    float2* agg1s = (float2*)(bufB + 400000);             // [400000 .. 600000)
    f4*     nd1   = (f4*)(bufB + 600000);                 // [600000 .. 1000000)
    float2* ed1   = (float2*)(bufB + 1000000);            // [1000000 .. 1200000)
    (void)ws_size; (void)in_sizes; (void)n_in; (void)out_size;

    k_init<<<1, 64, 0, stream>>>(stats);
    k_bnstats<<<256, 256, 0, stream>>>(h, stats);
    k_coef<<<1, 64, 0, stream>>>(W1, as1, ad1, coef);
    k_wprep<<<64, 256, 0, stream>>>(fw1, fw2, fw3, fw4, fw5, Wt, Wt5);

    // CSR build (round-5 proven path)
    k_hist<<<NBLK, 256, 0, stream>>>(ei, H);
    k_bscan1<<<1, 1024, 0, stream>>>(H, boff);
    k_bscan2<<<NBUCK, 64, 0, stream>>>(H, boff);
    k_part<<<NBLK, 256, 0, stream>>>(ei, H, pairs);
    k_bucket<<<NBUCK, 1024, 0, stream>>>(pairs, boff, rowptr, srcl);

    // GAT layer 1 (rank-2 path)
    k_prep1<<<(NN + 255) / 256, 256, 0, stream>>>(h, stats, gam, bet, coef, nd1, ed1);
    k_gat1<<<(NN + 255) / 256, 256, 0, stream>>>(nd1, ed1, rowptr, srcl, agg1a, agg1s);

    // layer-1 finalize + layer-2 transform (writes xp=bufA, es2v, ed2v)
    k_xform2f<<<(NN + 255) / 256, 256, 0, stream>>>(agg1a, agg1s, W1, b1, W2, as2, ad2,
                                                    bufA, es2v, ed2v);

    // GAT layer 2: fused exp, 8-deep load pipeline
    k_gat2<<<(NN * 64) / 256, 256, 0, stream>>>(bufA, es2v, ed2v, rowptr, srcl, b2, bufB);

    // MLP head
    k_mlp<<<(NN + 63) / 64, 256, 0, stream>>>(bufB, Wt, Wt5, fb1, fb2, fb3, fb4, fb5, out);
}

// Round 10
// 325.706 us; speedup vs baseline: 1.4188x; 1.0232x over previous
//
#include <hip/hip_runtime.h>
#include <hip/hip_fp16.h>
#include <math.h>

#define NN 100000
#define EE 1600000
#define ET (EE + NN)          // edges + self loops = 1,700,000
#define NEG 0.2f
#define MSTR 68               // k_mlp LDS row stride (floats)

// CSR-build geometry (round-3/5 proven path)
#define NBUCK 98              // ceil(NN/1024) buckets of 1024 dst nodes
#define NBLK 416              // ceil(ET/4096) partition blocks
#define BITEMS 4096           // items per partition block (256 thr x 16)

typedef float4 f4;

// ---------------- init: stats=0 ----------------
__global__ void k_init(float* stats) {
    int i = threadIdx.x;
    if (i < 4) stats[i] = 0.f;
}

// ---------------- BN statistics ----------------
__global__ void k_bnstats(const float* __restrict__ h, float* stats) {
    int gid = blockIdx.x * blockDim.x + threadIdx.x;
    int stride = gridDim.x * blockDim.x;
    float s0 = 0.f, s1 = 0.f, q0 = 0.f, q1 = 0.f;
    for (int i = gid; i < NN; i += stride) {
        float2 v = reinterpret_cast<const float2*>(h)[i];
        s0 += v.x; q0 += v.x * v.x;
        s1 += v.y; q1 += v.y * v.y;
    }
#pragma unroll
    for (int off = 32; off >= 1; off >>= 1) {
        s0 += __shfl_xor(s0, off);
        s1 += __shfl_xor(s1, off);
        q0 += __shfl_xor(q0, off);
        q1 += __shfl_xor(q1, off);
    }
    if ((threadIdx.x & 63) == 0) {
        atomicAdd(&stats[0], s0); atomicAdd(&stats[1], s1);
        atomicAdd(&stats[2], q0); atomicAdd(&stats[3], q1);
    }
}

// ---------------- layer-1 rank-2 attention coefficients ----------------
__global__ void k_coef(const float* __restrict__ W1, const float* __restrict__ as1,
                       const float* __restrict__ ad1, float* __restrict__ coef) {
    int t = threadIdx.x;
    if (t >= 8) return;
    int sd = t >> 2, hh = (t >> 1) & 1, i = t & 1;
    const float* a = sd ? ad1 : as1;
    float s = 0.f;
    for (int c = 0; c < 32; ++c) s += W1[(hh * 32 + c) * 2 + i] * a[hh * 32 + c];
    coef[t] = s;
}

// ---------------- pack MLP weights for wave-uniform contiguous s_load streams ----------------
__global__ void k_wprep(const float* __restrict__ w1, const float* __restrict__ w2,
                        const float* __restrict__ w3, const float* __restrict__ w4,
                        const float* __restrict__ w5,
                        float* __restrict__ Wt, float* __restrict__ Wt5) {
    int idx = blockIdx.x * blockDim.x + threadIdx.x;
    if (idx < 4 * 4096) {
        int L = idx >> 12;
        int r = idx & 4095;
        int q = r >> 10;
        int t = r & 1023;
        int i = t >> 4, j = t & 15;
        const float* W = (L == 0) ? w1 : (L == 1) ? w2 : (L == 2) ? w3 : w4;
        Wt[idx] = W[(q * 16 + j) * 64 + i];
    }
    if (idx < 1024) {
        int i = idx >> 4, c = idx & 15;
        int w = c >> 2, j = c & 3;
        int o = 3 * w + j;
        int ocnt = (w == 3) ? 2 : 3;
        Wt5[idx] = (j < ocnt) ? w5[o * 64 + i] : 0.f;
    }
}

// ---------------- CSR pass A: per-block bucket histogram ----------------
__global__ void __launch_bounds__(256) k_hist(const int* __restrict__ ei, int* __restrict__ H) {
    __shared__ int hist[NBUCK];
    int tid = threadIdx.x, blk = blockIdx.x;
    if (tid < NBUCK) hist[tid] = 0;
    __syncthreads();
    int base = blk * BITEMS;
#pragma unroll
    for (int it = 0; it < 16; ++it) {
        int i = base + it * 256 + tid;
        if (i < ET) {
            int d = (i < EE) ? ei[EE + i] : (i - EE);
            atomicAdd(&hist[d >> 10], 1);
        }
    }
    __syncthreads();
    if (tid < NBUCK) H[tid * NBLK + blk] = hist[tid];
}

// ---------------- CSR pass B1: bucket totals + base offsets (1 block) ----------------
__global__ void __launch_bounds__(1024) k_bscan1(const int* __restrict__ H, int* __restrict__ boff) {
    __shared__ int part[1024];
    __shared__ int btot[NBUCK];
    int tid = threadIdx.x;
    int b = tid >> 3, k = tid & 7;
    int s = 0;
    if (b < NBUCK)
        for (int blk = k; blk < NBLK; blk += 8) s += H[b * NBLK + blk];
    part[tid] = s;
    __syncthreads();
    if (tid < NBUCK) {
        int t = 0;
#pragma unroll
        for (int j = 0; j < 8; ++j) t += part[tid * 8 + j];
        btot[tid] = t;
    }
    __syncthreads();
    if (tid == 0) {
        int run = 0;
        for (int bb = 0; bb < NBUCK; ++bb) { boff[bb] = run; run += btot[bb]; }
        boff[NBUCK] = ET;
    }
}

// ---------------- CSR pass B2: per-(bucket,block) absolute offsets ----------------
__global__ void __launch_bounds__(64) k_bscan2(int* __restrict__ H, const int* __restrict__ boff) {
    int b = blockIdx.x, lane = threadIdx.x;
    int s = 0;
    int base_i = lane * 7;
#pragma unroll
    for (int j = 0; j < 7; ++j) {
        int idx = base_i + j;
        if (idx < NBLK) s += H[b * NBLK + idx];
    }
    int incl = s;
#pragma unroll
    for (int d = 1; d < 64; d <<= 1) {
        int n = __shfl_up(incl, d, 64);
        if (lane >= d) incl += n;
    }
    int run = boff[b] + incl - s;
#pragma unroll
    for (int j = 0; j < 7; ++j) {
        int idx = base_i + j;
        if (idx < NBLK) {
            int t = H[b * NBLK + idx];
            H[b * NBLK + idx] = run;
            run += t;
        }
    }
}

// ---------------- CSR pass C: partition edges into bucket regions ----------------
__global__ void __launch_bounds__(256) k_part(const int* __restrict__ ei, const int* __restrict__ H,
                                              unsigned* __restrict__ pairs) {
    __shared__ int cur[NBUCK];
    int tid = threadIdx.x, blk = blockIdx.x;
    if (tid < NBUCK) cur[tid] = H[tid * NBLK + blk];
    __syncthreads();
    int base = blk * BITEMS;
#pragma unroll
    for (int it = 0; it < 16; ++it) {
        int i = base + it * 256 + tid;
        if (i < ET) {
            int s, d;
            if (i < EE) { s = ei[i]; d = ei[EE + i]; }
            else { s = d = i - EE; }
            int b = d >> 10;
            int pos = atomicAdd(&cur[b], 1);
            pairs[pos] = (unsigned)s | ((unsigned)(d & 1023) << 17);
        }
    }
}

// ---------------- CSR pass D: per-bucket local CSR (rowptr + srcl) ----------------
__global__ void __launch_bounds__(1024) k_bucket(const unsigned* __restrict__ pairs,
                                                 const int* __restrict__ boff,
                                                 int* __restrict__ rowptr, int* __restrict__ srcl) {
    __shared__ int sh[1024];
    __shared__ int se[1024];
    int b = blockIdx.x, tid = threadIdx.x;
    int bb = boff[b], be = boff[b + 1];
    sh[tid] = 0;
    __syncthreads();
    for (int k = bb + tid; k < be; k += 1024) atomicAdd(&sh[pairs[k] >> 17], 1);
    __syncthreads();
    int deg = sh[tid];
    se[tid] = deg;
    __syncthreads();
    for (int off = 1; off < 1024; off <<= 1) {
        int t = (tid >= off) ? se[tid - off] : 0;
        __syncthreads();
        se[tid] += t;
        __syncthreads();
    }
    int excl = se[tid] - deg;
    int node = (b << 10) + tid;
    if (node < NN) rowptr[node] = bb + excl;
    sh[tid] = bb + excl;     // cursor
    __syncthreads();
    for (int k = bb + tid; k < be; k += 1024) {
        unsigned p = pairs[k];
        int pos = atomicAdd(&sh[p >> 17], 1);
        srcl[pos] = (int)(p & 0x1FFFFu);
    }
    if (b == 0 && tid == 0) rowptr[NN] = ET;
}

// ---------------- layer-1 prep: BN apply + rank-2 attention scalars ----------------
__global__ void k_prep1(const float* __restrict__ h, const float* __restrict__ stats,
                        const float* __restrict__ gamma, const float* __restrict__ beta,
                        const float* __restrict__ coef,
                        f4* __restrict__ nd1, float2* __restrict__ ed1) {
    int n = blockIdx.x * blockDim.x + threadIdx.x;
    if (n >= NN) return;
    const float inv = 1.f / (float)NN;
    float mu0 = stats[0] * inv, mu1 = stats[1] * inv;
    float v0 = stats[2] * inv - mu0 * mu0;
    float v1 = stats[3] * inv - mu1 * mu1;
    float g0 = rsqrtf(v0 + 1e-5f) * gamma[0];
    float g1 = rsqrtf(v1 + 1e-5f) * gamma[1];
    float2 hv = reinterpret_cast<const float2*>(h)[n];
    float x0 = (hv.x - mu0) * g0 + beta[0];
    float x1 = (hv.y - mu1) * g1 + beta[1];
    nd1[n] = make_float4(x0 * coef[0] + x1 * coef[1], x0 * coef[2] + x1 * coef[3], x0, x1);
    ed1[n] = make_float2(x0 * coef[4] + x1 * coef[5], x0 * coef[6] + x1 * coef[7]);
}

// ---------------- layer-1 GAT: thread per dst, 16B gather (L2-resident 1.6MB) ----------------
__global__ void __launch_bounds__(256) k_gat1(
    const f4* __restrict__ nd1, const float2* __restrict__ ed1,
    const int* __restrict__ rowptr, const int* __restrict__ srcl,
    f4* __restrict__ agg1a, float2* __restrict__ agg1s) {
    int n = blockIdx.x * blockDim.x + threadIdx.x;
    if (n >= NN) return;
    int beg = rowptr[n], end = rowptr[n + 1];
    float2 ed = ed1[n];
    float A0 = 0.f, B0 = 0.f, S0 = 0.f, A1 = 0.f, B1 = 0.f, S1 = 0.f;
    for (int k = beg; k < end; ++k) {
        int s = srcl[k];
        f4 p = nd1[s];
        float e0 = p.x + ed.x;
        float e1 = p.y + ed.y;
        e0 = (e0 > 0.f) ? e0 : NEG * e0;
        e1 = (e1 > 0.f) ? e1 : NEG * e1;
        float w0 = __expf(e0);
        float w1 = __expf(e1);
        A0 += w0 * p.z; B0 += w0 * p.w; S0 += w0;
        A1 += w1 * p.z; B1 += w1 * p.w; S1 += w1;
    }
    agg1a[n] = make_float4(A0, B0, A1, B1);
    agg1s[n] = make_float2(S0, S1);
}

// ---------------- layer-1 finalize + linear(64->64) + layer-2 attention scalars ----------------
// xp stored as FP16 rows (128B) to halve the layer-2 gather traffic; es/ed stay fp32.
__global__ void k_xform2f(const f4* __restrict__ agg1a, const float2* __restrict__ agg1s,
                          const float* __restrict__ W1, const float* __restrict__ b1,
                          const float* __restrict__ W, const float* __restrict__ a_s,
                          const float* __restrict__ a_d,
                          __half* __restrict__ xph, float2* __restrict__ es2v,
                          float2* __restrict__ ed2v) {
    int n = blockIdx.x * blockDim.x + threadIdx.x;
    if (n >= NN) return;
    f4 ag = agg1a[n];
    float2 sg = agg1s[n];
    float r0 = 1.f / (sg.x + 1e-16f);
    float r1 = 1.f / (sg.y + 1e-16f);
    float x[64];
#pragma unroll
    for (int f = 0; f < 64; ++f) {
        float A = (f < 32) ? ag.x : ag.z;
        float B = (f < 32) ? ag.y : ag.w;
        float r = (f < 32) ? r0 : r1;
        x[f] = fmaxf((A * W1[2 * f] + B * W1[2 * f + 1]) * r + b1[f], 0.f);
    }
    float es0 = 0.f, es1 = 0.f, ed0 = 0.f, ed1 = 0.f;
    __half2* xo = reinterpret_cast<__half2*>(xph + (size_t)n * 64);
#pragma unroll 1
    for (int fq = 0; fq < 16; ++fq) {
        float vq[4];
#pragma unroll
        for (int j = 0; j < 4; ++j) {
            int f = 4 * fq + j;
            float acc = 0.f;
#pragma unroll
            for (int i = 0; i < 64; ++i) acc += W[f * 64 + i] * x[i];
            vq[j] = acc;
            float ts = acc * a_s[f], td = acc * a_d[f];
            if (fq < 8) { es0 += ts; ed0 += td; } else { es1 += ts; ed1 += td; }
        }
        xo[2 * fq]     = __floats2half2_rn(vq[0], vq[1]);
        xo[2 * fq + 1] = __floats2half2_rn(vq[2], vq[3]);
    }
    es2v[n] = make_float2(es0, es1);
    ed2v[n] = make_float2(ed0, ed1);
}

// ---------------- layer-2 GAT: wave per dst, fused exp, interleaved unroll-4, fp16 gather ----------------
__global__ void __launch_bounds__(256) k_gat2(
    const __half* __restrict__ xph, const float2* __restrict__ es2v,
    const float2* __restrict__ ed2v,
    const int* __restrict__ rowptr, const int* __restrict__ srcl,
    const float* __restrict__ bias, float* __restrict__ y) {
    int wid = (blockIdx.x * blockDim.x + threadIdx.x) >> 6;
    int lane = threadIdx.x & 63;
    if (wid >= NN) return;
    bool hi = lane >= 32;
    int beg = rowptr[wid], end = rowptr[wid + 1];
    float2 edp = ed2v[wid];
    float edv = hi ? edp.y : edp.x;
    float sum = 0.f, acc = 0.f;
    int k = beg;
    for (; k + 4 <= end; k += 4) {
        int s0 = srcl[k], s1 = srcl[k + 1], s2 = srcl[k + 2], s3 = srcl[k + 3];
        float2 p0 = es2v[s0];
        float2 p1 = es2v[s1];
        float2 p2 = es2v[s2];
        float2 p3 = es2v[s3];
        float x0 = __half2float(xph[(size_t)s0 * 64 + lane]);
        float x1 = __half2float(xph[(size_t)s1 * 64 + lane]);
        float x2 = __half2float(xph[(size_t)s2 * 64 + lane]);
        float x3 = __half2float(xph[(size_t)s3 * 64 + lane]);
        float e0 = (hi ? p0.y : p0.x) + edv;
        float e1 = (hi ? p1.y : p1.x) + edv;
        float e2 = (hi ? p2.y : p2.x) + edv;
        float e3 = (hi ? p3.y : p3.x) + edv;
        e0 = (e0 > 0.f) ? e0 : NEG * e0;
        e1 = (e1 > 0.f) ? e1 : NEG * e1;
        e2 = (e2 > 0.f) ? e2 : NEG * e2;
        e3 = (e3 > 0.f) ? e3 : NEG * e3;
        float w0 = __expf(e0);
        float w1 = __expf(e1);
        float w2 = __expf(e2);
        float w3 = __expf(e3);
        sum += (w0 + w1) + (w2 + w3);
        acc += (w0 * x0 + w1 * x1) + (w2 * x2 + w3 * x3);
    }
    for (; k < end; ++k) {
        int s = srcl[k];
        float2 p = es2v[s];
        float e = (hi ? p.y : p.x) + edv;
        e = (e > 0.f) ? e : NEG * e;
        float w = __expf(e);
        sum += w;
        acc += w * __half2float(xph[(size_t)s * 64 + lane]);
    }
    float r = acc / (sum + 1e-16f) + bias[lane];
    y[(size_t)wid * 64 + lane] = fmaxf(r, 0.f);               // post-GAT ReLU
}

// ---------------- fused 5-layer MLP: 4 waves/block, wave w owns outputs [16w,16w+16) ----------------
__device__ __forceinline__ void mlayer(const float* __restrict__ Wq, const float* __restrict__ B,
                                       int o0, const float* __restrict__ xrow, float* acc) {
#pragma unroll
    for (int j = 0; j < 16; ++j) acc[j] = B[o0 + j];
#pragma unroll
    for (int c = 0; c < 4; ++c) {
        float xc[16];
#pragma unroll
        for (int q = 0; q < 4; ++q) {
            f4 t = *reinterpret_cast<const f4*>(&xrow[c * 16 + 4 * q]);
            xc[4 * q] = t.x; xc[4 * q + 1] = t.y; xc[4 * q + 2] = t.z; xc[4 * q + 3] = t.w;
        }
#pragma unroll
        for (int i = 0; i < 16; ++i) {
            const float* row = &Wq[(c * 16 + i) * 16];   // 64 B contiguous, wave-uniform
#pragma unroll
            for (int j = 0; j < 16; ++j) acc[j] += row[j] * xc[i];
        }
    }
}

__global__ void __launch_bounds__(256) k_mlp(
    const float* __restrict__ hin,
    const float* __restrict__ Wt, const float* __restrict__ Wt5,
    const float* __restrict__ b1, const float* __restrict__ b2,
    const float* __restrict__ b3, const float* __restrict__ b4,
    const float* __restrict__ b5,
    float* __restrict__ out) {
    __shared__ float xs[64 * MSTR];
    int lane = threadIdx.x & 63;
    int w = __builtin_amdgcn_readfirstlane(threadIdx.x >> 6);
    int nodeBase = blockIdx.x * 64;
    int node = nodeBase + lane;
    int o0 = w * 16;
    const float* xrow = &xs[lane * MSTR];

#pragma unroll
    for (int i = 0; i < 4; ++i) {
        int v = threadIdx.x + 256 * i;
        int nl = v >> 4;
        int f = (v & 15) << 2;
        f4 t4 = make_float4(0.f, 0.f, 0.f, 0.f);
        if (nodeBase + nl < NN)
            t4 = reinterpret_cast<const f4*>(hin)[(size_t)(nodeBase + nl) * 16 + (v & 15)];
        *reinterpret_cast<f4*>(&xs[nl * MSTR + f]) = t4;
    }
    __syncthreads();

    float acc[16];
#define MLP_LAYER(L, Bp)                                                         \
    mlayer(Wt + ((L) * 4 + w) * 1024, Bp, o0, xrow, acc);                        \
    __syncthreads();                                                             \
    _Pragma("unroll")                                                            \
    for (int j = 0; j < 16; j += 4)                                              \
        *reinterpret_cast<f4*>(&xs[lane * MSTR + o0 + j]) =                      \
            make_float4(fmaxf(acc[j], 0.f), fmaxf(acc[j + 1], 0.f),              \
                        fmaxf(acc[j + 2], 0.f), fmaxf(acc[j + 3], 0.f));         \
    __syncthreads();

    MLP_LAYER(0, b1)
    MLP_LAYER(1, b2)
    MLP_LAYER(2, b3)
    MLP_LAYER(3, b4)
#undef MLP_LAYER

    int ocnt = (w == 3) ? 2 : 3;
    int ob = w * 3;
    float a5[3];
#pragma unroll
    for (int j = 0; j < 3; ++j) a5[j] = (j < ocnt) ? b5[ob + j] : 0.f;
#pragma unroll
    for (int c = 0; c < 4; ++c) {
        float xc[16];
#pragma unroll
        for (int q = 0; q < 4; ++q) {
            f4 t = *reinterpret_cast<const f4*>(&xrow[c * 16 + 4 * q]);
            xc[4 * q] = t.x; xc[4 * q + 1] = t.y; xc[4 * q + 2] = t.z; xc[4 * q + 3] = t.w;
        }
#pragma unroll
        for (int i = 0; i < 16; ++i) {
            const float* row = &Wt5[(c * 16 + i) * 16 + 4 * w];
#pragma unroll
            for (int j = 0; j < 3; ++j) a5[j] += row[j] * xc[i];
        }
    }
    if (node < NN) {
        for (int j = 0; j < ocnt; ++j) out[(size_t)node * 11 + ob + j] = a5[j];
    }
}

// ---------------- launch ----------------
extern "C" void kernel_launch(void* const* d_in, const int* in_sizes, int n_in,
                              void* d_out, int out_size, void* d_ws, size_t ws_size,
                              hipStream_t stream) {
    const float* h   = (const float*)d_in[0];
    const int*   ei  = (const int*)d_in[1];
    const float* gam = (const float*)d_in[2];
    const float* bet = (const float*)d_in[3];
    const float* W1  = (const float*)d_in[4];
    const float* as1 = (const float*)d_in[5];
    const float* ad1 = (const float*)d_in[6];
    const float* b1  = (const float*)d_in[7];
    const float* W2  = (const float*)d_in[8];
    const float* as2 = (const float*)d_in[9];
    const float* ad2 = (const float*)d_in[10];
    const float* b2  = (const float*)d_in[11];
    const float* fw1 = (const float*)d_in[12];
    const float* fb1 = (const float*)d_in[13];
    const float* fw2 = (const float*)d_in[14];
    const float* fb2 = (const float*)d_in[15];
    const float* fw3 = (const float*)d_in[16];
    const float* fb3 = (const float*)d_in[17];
    const float* fw4 = (const float*)d_in[18];
    const float* fb4 = (const float*)d_in[19];
    const float* fw5 = (const float*)d_in[20];
    const float* fb5 = (const float*)d_in[21];
    float* out = (float*)d_out;

    char* ws = (char*)d_ws;
    size_t off = 0;
    auto alloc = [&](size_t bytes) -> char* {
        char* p = ws + off;
        off += (bytes + 255) & ~(size_t)255;
        return p;
    };
    float* stats  = (float*)alloc(4 * sizeof(float));
    float* coef   = (float*)alloc(8 * sizeof(float));
    int*   H      = (int*)alloc((size_t)NBUCK * NBLK * sizeof(int));
    int*   boff   = (int*)alloc((size_t)(NBUCK + 1) * sizeof(int));
    int*   rowptr = (int*)alloc((size_t)(NN + 1) * sizeof(int));
    int*   srcl   = (int*)alloc((size_t)ET * sizeof(int));
    float2* es2v  = (float2*)alloc((size_t)NN * sizeof(float2));
    float2* ed2v  = (float2*)alloc((size_t)NN * sizeof(float2));
    float* Wt     = (float*)alloc((size_t)4 * 4096 * sizeof(float));
    float* Wt5    = (float*)alloc((size_t)1024 * sizeof(float));
    float* bufA   = (float*)alloc((size_t)NN * 64 * sizeof(float));   // xp fp16 rows (12.8MB used)
    float* bufB   = (float*)alloc((size_t)NN * 64 * sizeof(float));
    // aliases (dead before their hosts are written):
    unsigned* pairs = (unsigned*)bufA;                    // dead after k_bucket; bufA then holds xph
    __half* xph   = (__half*)bufA;
    f4*     agg1a = (f4*)bufB;                            // floats [0 .. 400000)
    float2* agg1s = (float2*)(bufB + 400000);             // [400000 .. 600000)
    f4*     nd1   = (f4*)(bufB + 600000);                 // [600000 .. 1000000)
    float2* ed1   = (float2*)(bufB + 1000000);            // [1000000 .. 1200000)
    (void)ws_size; (void)in_sizes; (void)n_in; (void)out_size;

    k_init<<<1, 64, 0, stream>>>(stats);
    k_bnstats<<<256, 256, 0, stream>>>(h, stats);
    k_coef<<<1, 64, 0, stream>>>(W1, as1, ad1, coef);
    k_wprep<<<64, 256, 0, stream>>>(fw1, fw2, fw3, fw4, fw5, Wt, Wt5);

    // CSR build (round-5 proven path)
    k_hist<<<NBLK, 256, 0, stream>>>(ei, H);
    k_bscan1<<<1, 1024, 0, stream>>>(H, boff);
    k_bscan2<<<NBUCK, 64, 0, stream>>>(H, boff);
    k_part<<<NBLK, 256, 0, stream>>>(ei, H, pairs);
    k_bucket<<<NBUCK, 1024, 0, stream>>>(pairs, boff, rowptr, srcl);

    // GAT layer 1 (rank-2 path)
    k_prep1<<<(NN + 255) / 256, 256, 0, stream>>>(h, stats, gam, bet, coef, nd1, ed1);
    k_gat1<<<(NN + 255) / 256, 256, 0, stream>>>(nd1, ed1, rowptr, srcl, agg1a, agg1s);

    // layer-1 finalize + layer-2 transform (writes xph=bufA fp16, es2v, ed2v)
    k_xform2f<<<(NN + 255) / 256, 256, 0, stream>>>(agg1a, agg1s, W1, b1, W2, as2, ad2,
                                                    xph, es2v, ed2v);

    // GAT layer 2: fused exp, interleaved unroll-4, fp16 gather
    k_gat2<<<(NN * 64) / 256, 256, 0, stream>>>(xph, es2v, ed2v, rowptr, srcl, b2, bufB);

    // MLP head
    k_mlp<<<(NN + 63) / 64, 256, 0, stream>>>(bufB, Wt, Wt5, fb1, fb2, fb3, fb4, fb5, out);
}

// Round 11
// 300.598 us; speedup vs baseline: 1.5373x; 1.0835x over previous
//
#include <hip/hip_runtime.h>
#include <hip/hip_fp16.h>
#include <math.h>

#define NN 100000
#define EE 1600000
#define ET (EE + NN)          // edges + self loops = 1,700,000
#define NEG 0.2f
#define MSTR 68               // k_mlp LDS row stride (floats)

// CSR-build geometry (round-3/5 proven path)
#define NBUCK 98              // ceil(NN/1024) buckets of 1024 dst nodes
#define NBLK 416              // ceil(ET/4096) partition blocks
#define BITEMS 4096           // items per partition block (256 thr x 16)

typedef float4 f4;

// ---------------- init: stats=0 ----------------
__global__ void k_init(float* stats) {
    int i = threadIdx.x;
    if (i < 4) stats[i] = 0.f;
}

// ---------------- BN statistics ----------------
__global__ void k_bnstats(const float* __restrict__ h, float* stats) {
    int gid = blockIdx.x * blockDim.x + threadIdx.x;
    int stride = gridDim.x * blockDim.x;
    float s0 = 0.f, s1 = 0.f, q0 = 0.f, q1 = 0.f;
    for (int i = gid; i < NN; i += stride) {
        float2 v = reinterpret_cast<const float2*>(h)[i];
        s0 += v.x; q0 += v.x * v.x;
        s1 += v.y; q1 += v.y * v.y;
    }
#pragma unroll
    for (int off = 32; off >= 1; off >>= 1) {
        s0 += __shfl_xor(s0, off);
        s1 += __shfl_xor(s1, off);
        q0 += __shfl_xor(q0, off);
        q1 += __shfl_xor(q1, off);
    }
    if ((threadIdx.x & 63) == 0) {
        atomicAdd(&stats[0], s0); atomicAdd(&stats[1], s1);
        atomicAdd(&stats[2], q0); atomicAdd(&stats[3], q1);
    }
}

// ---------------- layer-1 rank-2 attention coefficients ----------------
__global__ void k_coef(const float* __restrict__ W1, const float* __restrict__ as1,
                       const float* __restrict__ ad1, float* __restrict__ coef) {
    int t = threadIdx.x;
    if (t >= 8) return;
    int sd = t >> 2, hh = (t >> 1) & 1, i = t & 1;
    const float* a = sd ? ad1 : as1;
    float s = 0.f;
    for (int c = 0; c < 32; ++c) s += W1[(hh * 32 + c) * 2 + i] * a[hh * 32 + c];
    coef[t] = s;
}

// ---------------- pack MLP weights for wave-uniform contiguous s_load streams ----------------
__global__ void k_wprep(const float* __restrict__ w1, const float* __restrict__ w2,
                        const float* __restrict__ w3, const float* __restrict__ w4,
                        const float* __restrict__ w5,
                        float* __restrict__ Wt, float* __restrict__ Wt5) {
    int idx = blockIdx.x * blockDim.x + threadIdx.x;
    if (idx < 4 * 4096) {
        int L = idx >> 12;
        int r = idx & 4095;
        int q = r >> 10;
        int t = r & 1023;
        int i = t >> 4, j = t & 15;
        const float* W = (L == 0) ? w1 : (L == 1) ? w2 : (L == 2) ? w3 : w4;
        Wt[idx] = W[(q * 16 + j) * 64 + i];
    }
    if (idx < 1024) {
        int i = idx >> 4, c = idx & 15;
        int w = c >> 2, j = c & 3;
        int o = 3 * w + j;
        int ocnt = (w == 3) ? 2 : 3;
        Wt5[idx] = (j < ocnt) ? w5[o * 64 + i] : 0.f;
    }
}

// ---------------- CSR pass A: per-block bucket histogram ----------------
__global__ void __launch_bounds__(256) k_hist(const int* __restrict__ ei, int* __restrict__ H) {
    __shared__ int hist[NBUCK];
    int tid = threadIdx.x, blk = blockIdx.x;
    if (tid < NBUCK) hist[tid] = 0;
    __syncthreads();
    int base = blk * BITEMS;
#pragma unroll
    for (int it = 0; it < 16; ++it) {
        int i = base + it * 256 + tid;
        if (i < ET) {
            int d = (i < EE) ? ei[EE + i] : (i - EE);
            atomicAdd(&hist[d >> 10], 1);
        }
    }
    __syncthreads();
    if (tid < NBUCK) H[tid * NBLK + blk] = hist[tid];
}

// ---------------- CSR pass B1: bucket totals + base offsets (1 block) ----------------
__global__ void __launch_bounds__(1024) k_bscan1(const int* __restrict__ H, int* __restrict__ boff) {
    __shared__ int part[1024];
    __shared__ int btot[NBUCK];
    int tid = threadIdx.x;
    int b = tid >> 3, k = tid & 7;
    int s = 0;
    if (b < NBUCK)
        for (int blk = k; blk < NBLK; blk += 8) s += H[b * NBLK + blk];
    part[tid] = s;
    __syncthreads();
    if (tid < NBUCK) {
        int t = 0;
#pragma unroll
        for (int j = 0; j < 8; ++j) t += part[tid * 8 + j];
        btot[tid] = t;
    }
    __syncthreads();
    if (tid == 0) {
        int run = 0;
        for (int bb = 0; bb < NBUCK; ++bb) { boff[bb] = run; run += btot[bb]; }
        boff[NBUCK] = ET;
    }
}

// ---------------- CSR pass B2: per-(bucket,block) absolute offsets ----------------
__global__ void __launch_bounds__(64) k_bscan2(int* __restrict__ H, const int* __restrict__ boff) {
    int b = blockIdx.x, lane = threadIdx.x;
    int s = 0;
    int base_i = lane * 7;
#pragma unroll
    for (int j = 0; j < 7; ++j) {
        int idx = base_i + j;
        if (idx < NBLK) s += H[b * NBLK + idx];
    }
    int incl = s;
#pragma unroll
    for (int d = 1; d < 64; d <<= 1) {
        int n = __shfl_up(incl, d, 64);
        if (lane >= d) incl += n;
    }
    int run = boff[b] + incl - s;
#pragma unroll
    for (int j = 0; j < 7; ++j) {
        int idx = base_i + j;
        if (idx < NBLK) {
            int t = H[b * NBLK + idx];
            H[b * NBLK + idx] = run;
            run += t;
        }
    }
}

// ---------------- CSR pass C: partition edges into bucket regions ----------------
__global__ void __launch_bounds__(256) k_part(const int* __restrict__ ei, const int* __restrict__ H,
                                              unsigned* __restrict__ pairs) {
    __shared__ int cur[NBUCK];
    int tid = threadIdx.x, blk = blockIdx.x;
    if (tid < NBUCK) cur[tid] = H[tid * NBLK + blk];
    __syncthreads();
    int base = blk * BITEMS;
#pragma unroll
    for (int it = 0; it < 16; ++it) {
        int i = base + it * 256 + tid;
        if (i < ET) {
            int s, d;
            if (i < EE) { s = ei[i]; d = ei[EE + i]; }
            else { s = d = i - EE; }
            int b = d >> 10;
            int pos = atomicAdd(&cur[b], 1);
            pairs[pos] = (unsigned)s | ((unsigned)(d & 1023) << 17);
        }
    }
}

// ---------------- CSR pass D: per-bucket local CSR (rowptr + srcl) ----------------
__global__ void __launch_bounds__(1024) k_bucket(const unsigned* __restrict__ pairs,
                                                 const int* __restrict__ boff,
                                                 int* __restrict__ rowptr, int* __restrict__ srcl) {
    __shared__ int sh[1024];
    __shared__ int se[1024];
    int b = blockIdx.x, tid = threadIdx.x;
    int bb = boff[b], be = boff[b + 1];
    sh[tid] = 0;
    __syncthreads();
    for (int k = bb + tid; k < be; k += 1024) atomicAdd(&sh[pairs[k] >> 17], 1);
    __syncthreads();
    int deg = sh[tid];
    se[tid] = deg;
    __syncthreads();
    for (int off = 1; off < 1024; off <<= 1) {
        int t = (tid >= off) ? se[tid - off] : 0;
        __syncthreads();
        se[tid] += t;
        __syncthreads();
    }
    int excl = se[tid] - deg;
    int node = (b << 10) + tid;
    if (node < NN) rowptr[node] = bb + excl;
    sh[tid] = bb + excl;     // cursor
    __syncthreads();
    for (int k = bb + tid; k < be; k += 1024) {
        unsigned p = pairs[k];
        int pos = atomicAdd(&sh[p >> 17], 1);
        srcl[pos] = (int)(p & 0x1FFFFu);
    }
    if (b == 0 && tid == 0) rowptr[NN] = ET;
}

// ---------------- layer-1 prep: BN apply + rank-2 attention scalars ----------------
__global__ void k_prep1(const float* __restrict__ h, const float* __restrict__ stats,
                        const float* __restrict__ gamma, const float* __restrict__ beta,
                        const float* __restrict__ coef,
                        f4* __restrict__ nd1, float2* __restrict__ ed1) {
    int n = blockIdx.x * blockDim.x + threadIdx.x;
    if (n >= NN) return;
    const float inv = 1.f / (float)NN;
    float mu0 = stats[0] * inv, mu1 = stats[1] * inv;
    float v0 = stats[2] * inv - mu0 * mu0;
    float v1 = stats[3] * inv - mu1 * mu1;
    float g0 = rsqrtf(v0 + 1e-5f) * gamma[0];
    float g1 = rsqrtf(v1 + 1e-5f) * gamma[1];
    float2 hv = reinterpret_cast<const float2*>(h)[n];
    float x0 = (hv.x - mu0) * g0 + beta[0];
    float x1 = (hv.y - mu1) * g1 + beta[1];
    nd1[n] = make_float4(x0 * coef[0] + x1 * coef[1], x0 * coef[2] + x1 * coef[3], x0, x1);
    ed1[n] = make_float2(x0 * coef[4] + x1 * coef[5], x0 * coef[6] + x1 * coef[7]);
}

// ---------------- layer-1 GAT: thread per dst, 16B gather (L2-resident 1.6MB) ----------------
__global__ void __launch_bounds__(256) k_gat1(
    const f4* __restrict__ nd1, const float2* __restrict__ ed1,
    const int* __restrict__ rowptr, const int* __restrict__ srcl,
    f4* __restrict__ agg1a, float2* __restrict__ agg1s) {
    int n = blockIdx.x * blockDim.x + threadIdx.x;
    if (n >= NN) return;
    int beg = rowptr[n], end = rowptr[n + 1];
    float2 ed = ed1[n];
    float A0 = 0.f, B0 = 0.f, S0 = 0.f, A1 = 0.f, B1 = 0.f, S1 = 0.f;
    for (int k = beg; k < end; ++k) {
        int s = srcl[k];
        f4 p = nd1[s];
        float e0 = p.x + ed.x;
        float e1 = p.y + ed.y;
        e0 = (e0 > 0.f) ? e0 : NEG * e0;
        e1 = (e1 > 0.f) ? e1 : NEG * e1;
        float w0 = __expf(e0);
        float w1 = __expf(e1);
        A0 += w0 * p.z; B0 += w0 * p.w; S0 += w0;
        A1 += w1 * p.z; B1 += w1 * p.w; S1 += w1;
    }
    agg1a[n] = make_float4(A0, B0, A1, B1);
    agg1s[n] = make_float2(S0, S1);
}

// ---------------- layer-1 finalize + linear(64->64) + layer-2 attention scalars ----------------
// xp stored as FP16 rows (128B); es/ed stay fp32.
__global__ void k_xform2f(const f4* __restrict__ agg1a, const float2* __restrict__ agg1s,
                          const float* __restrict__ W1, const float* __restrict__ b1,
                          const float* __restrict__ W, const float* __restrict__ a_s,
                          const float* __restrict__ a_d,
                          __half* __restrict__ xph, float2* __restrict__ es2v,
                          float2* __restrict__ ed2v) {
    int n = blockIdx.x * blockDim.x + threadIdx.x;
    if (n >= NN) return;
    f4 ag = agg1a[n];
    float2 sg = agg1s[n];
    float r0 = 1.f / (sg.x + 1e-16f);
    float r1 = 1.f / (sg.y + 1e-16f);
    float x[64];
#pragma unroll
    for (int f = 0; f < 64; ++f) {
        float A = (f < 32) ? ag.x : ag.z;
        float B = (f < 32) ? ag.y : ag.w;
        float r = (f < 32) ? r0 : r1;
        x[f] = fmaxf((A * W1[2 * f] + B * W1[2 * f + 1]) * r + b1[f], 0.f);
    }
    float es0 = 0.f, es1 = 0.f, ed0 = 0.f, ed1 = 0.f;
    __half2* xo = reinterpret_cast<__half2*>(xph + (size_t)n * 64);
#pragma unroll 1
    for (int fq = 0; fq < 16; ++fq) {
        float vq[4];
#pragma unroll
        for (int j = 0; j < 4; ++j) {
            int f = 4 * fq + j;
            float acc = 0.f;
#pragma unroll
            for (int i = 0; i < 64; ++i) acc += W[f * 64 + i] * x[i];
            vq[j] = acc;
            float ts = acc * a_s[f], td = acc * a_d[f];
            if (fq < 8) { es0 += ts; ed0 += td; } else { es1 += ts; ed1 += td; }
        }
        xo[2 * fq]     = __floats2half2_rn(vq[0], vq[1]);
        xo[2 * fq + 1] = __floats2half2_rn(vq[2], vq[3]);
    }
    es2v[n] = make_float2(es0, es1);
    ed2v[n] = make_float2(ed0, ed1);
}

// ---------------- layer-2 GAT: wave per dst, PAIRED edges ----------------
// Lanes 0-31 process even-slot edges, lanes 32-63 odd-slot edges of the SAME dst.
// Each lane handles 2 channels (half2, 4B) -> one load instruction fetches 2 edges' rows.
// Unroll-4 pairs = 8 edges in flight per wave (2x the old depth).
__global__ void __launch_bounds__(256) k_gat2(
    const __half* __restrict__ xph, const float2* __restrict__ es2v,
    const float2* __restrict__ ed2v,
    const int* __restrict__ rowptr, const int* __restrict__ srcl,
    const float* __restrict__ bias, float* __restrict__ y) {
    int wid = (blockIdx.x * blockDim.x + threadIdx.x) >> 6;
    int lane = threadIdx.x & 63;
    if (wid >= NN) return;
    int l5 = lane & 31;            // channel pair index: channels 2*l5, 2*l5+1
    int hs = lane >> 5;            // 0: even slots, 1: odd slots
    bool headhi = l5 >= 16;        // channels >=32 -> head 1
    int ch = 2 * l5;
    float2 edp = ed2v[wid];
    float edv = headhi ? edp.y : edp.x;
    int beg = rowptr[wid], end = rowptr[wid + 1];
    float sum = 0.f, a0 = 0.f, a1 = 0.f;
    int k = beg;

#define GPAIR(kk)                                                                 \
    {                                                                             \
        int s_ = srcl[(kk) + hs];                                                 \
        float2 ep_ = es2v[s_];                                                    \
        unsigned xr_ = *reinterpret_cast<const unsigned*>(&xph[(size_t)s_ * 64 + ch]); \
        float e_ = (headhi ? ep_.y : ep_.x) + edv;                                \
        e_ = (e_ > 0.f) ? e_ : NEG * e_;                                          \
        float w_ = __expf(e_);                                                    \
        float2 xv_ = __half22float2(*reinterpret_cast<const __half2*>(&xr_));     \
        sum += w_; a0 += w_ * xv_.x; a1 += w_ * xv_.y;                            \
    }

    for (; k + 8 <= end; k += 8) {
        GPAIR(k) GPAIR(k + 2) GPAIR(k + 4) GPAIR(k + 6)
    }
    for (; k < end; k += 2) {
        int idx = k + hs;
        bool valid = idx < end;
        int s_ = srcl[valid ? idx : k];
        float2 ep_ = es2v[s_];
        unsigned xr_ = *reinterpret_cast<const unsigned*>(&xph[(size_t)s_ * 64 + ch]);
        float e_ = (headhi ? ep_.y : ep_.x) + edv;
        e_ = (e_ > 0.f) ? e_ : NEG * e_;
        float w_ = valid ? __expf(e_) : 0.f;
        float2 xv_ = __half22float2(*reinterpret_cast<const __half2*>(&xr_));
        sum += w_; a0 += w_ * xv_.x; a1 += w_ * xv_.y;
    }
#undef GPAIR

    // combine even/odd halves (lane l <-> l+32 hold same channels, same head)
    sum += __shfl_xor(sum, 32);
    a0  += __shfl_xor(a0, 32);
    a1  += __shfl_xor(a1, 32);
    if (lane < 32) {
        float rs = 1.f / (sum + 1e-16f);
        float r0 = fmaxf(a0 * rs + bias[ch], 0.f);
        float r1 = fmaxf(a1 * rs + bias[ch + 1], 0.f);
        *reinterpret_cast<float2*>(&y[(size_t)wid * 64 + ch]) = make_float2(r0, r1);
    }
}

// ---------------- fused 5-layer MLP: 4 waves/block, wave w owns outputs [16w,16w+16) ----------------
__device__ __forceinline__ void mlayer(const float* __restrict__ Wq, const float* __restrict__ B,
                                       int o0, const float* __restrict__ xrow, float* acc) {
#pragma unroll
    for (int j = 0; j < 16; ++j) acc[j] = B[o0 + j];
#pragma unroll
    for (int c = 0; c < 4; ++c) {
        float xc[16];
#pragma unroll
        for (int q = 0; q < 4; ++q) {
            f4 t = *reinterpret_cast<const f4*>(&xrow[c * 16 + 4 * q]);
            xc[4 * q] = t.x; xc[4 * q + 1] = t.y; xc[4 * q + 2] = t.z; xc[4 * q + 3] = t.w;
        }
#pragma unroll
        for (int i = 0; i < 16; ++i) {
            const float* row = &Wq[(c * 16 + i) * 16];   // 64 B contiguous, wave-uniform
#pragma unroll
            for (int j = 0; j < 16; ++j) acc[j] += row[j] * xc[i];
        }
    }
}

__global__ void __launch_bounds__(256) k_mlp(
    const float* __restrict__ hin,
    const float* __restrict__ Wt, const float* __restrict__ Wt5,
    const float* __restrict__ b1, const float* __restrict__ b2,
    const float* __restrict__ b3, const float* __restrict__ b4,
    const float* __restrict__ b5,
    float* __restrict__ out) {
    __shared__ float xs[64 * MSTR];
    int lane = threadIdx.x & 63;
    int w = __builtin_amdgcn_readfirstlane(threadIdx.x >> 6);
    int nodeBase = blockIdx.x * 64;
    int node = nodeBase + lane;
    int o0 = w * 16;
    const float* xrow = &xs[lane * MSTR];

#pragma unroll
    for (int i = 0; i < 4; ++i) {
        int v = threadIdx.x + 256 * i;
        int nl = v >> 4;
        int f = (v & 15) << 2;
        f4 t4 = make_float4(0.f, 0.f, 0.f, 0.f);
        if (nodeBase + nl < NN)
            t4 = reinterpret_cast<const f4*>(hin)[(size_t)(nodeBase + nl) * 16 + (v & 15)];
        *reinterpret_cast<f4*>(&xs[nl * MSTR + f]) = t4;
    }
    __syncthreads();

    float acc[16];
#define MLP_LAYER(L, Bp)                                                         \
    mlayer(Wt + ((L) * 4 + w) * 1024, Bp, o0, xrow, acc);                        \
    __syncthreads();                                                             \
    _Pragma("unroll")                                                            \
    for (int j = 0; j < 16; j += 4)                                              \
        *reinterpret_cast<f4*>(&xs[lane * MSTR + o0 + j]) =                      \
            make_float4(fmaxf(acc[j], 0.f), fmaxf(acc[j + 1], 0.f),              \
                        fmaxf(acc[j + 2], 0.f), fmaxf(acc[j + 3], 0.f));         \
    __syncthreads();

    MLP_LAYER(0, b1)
    MLP_LAYER(1, b2)
    MLP_LAYER(2, b3)
    MLP_LAYER(3, b4)
#undef MLP_LAYER

    int ocnt = (w == 3) ? 2 : 3;
    int ob = w * 3;
    float a5[3];
#pragma unroll
    for (int j = 0; j < 3; ++j) a5[j] = (j < ocnt) ? b5[ob + j] : 0.f;
#pragma unroll
    for (int c = 0; c < 4; ++c) {
        float xc[16];
#pragma unroll
        for (int q = 0; q < 4; ++q) {
            f4 t = *reinterpret_cast<const f4*>(&xrow[c * 16 + 4 * q]);
            xc[4 * q] = t.x; xc[4 * q + 1] = t.y; xc[4 * q + 2] = t.z; xc[4 * q + 3] = t.w;
        }
#pragma unroll
        for (int i = 0; i < 16; ++i) {
            const float* row = &Wt5[(c * 16 + i) * 16 + 4 * w];
#pragma unroll
            for (int j = 0; j < 3; ++j) a5[j] += row[j] * xc[i];
        }
    }
    if (node < NN) {
        for (int j = 0; j < ocnt; ++j) out[(size_t)node * 11 + ob + j] = a5[j];
    }
}

// ---------------- launch ----------------
extern "C" void kernel_launch(void* const* d_in, const int* in_sizes, int n_in,
                              void* d_out, int out_size, void* d_ws, size_t ws_size,
                              hipStream_t stream) {
    const float* h   = (const float*)d_in[0];
    const int*   ei  = (const int*)d_in[1];
    const float* gam = (const float*)d_in[2];
    const float* bet = (const float*)d_in[3];
    const float* W1  = (const float*)d_in[4];
    const float* as1 = (const float*)d_in[5];
    const float* ad1 = (const float*)d_in[6];
    const float* b1  = (const float*)d_in[7];
    const float* W2  = (const float*)d_in[8];
    const float* as2 = (const float*)d_in[9];
    const float* ad2 = (const float*)d_in[10];
    const float* b2  = (const float*)d_in[11];
    const float* fw1 = (const float*)d_in[12];
    const float* fb1 = (const float*)d_in[13];
    const float* fw2 = (const float*)d_in[14];
    const float* fb2 = (const float*)d_in[15];
    const float* fw3 = (const float*)d_in[16];
    const float* fb3 = (const float*)d_in[17];
    const float* fw4 = (const float*)d_in[18];
    const float* fb4 = (const float*)d_in[19];
    const float* fw5 = (const float*)d_in[20];
    const float* fb5 = (const float*)d_in[21];
    float* out = (float*)d_out;

    char* ws = (char*)d_ws;
    size_t off = 0;
    auto alloc = [&](size_t bytes) -> char* {
        char* p = ws + off;
        off += (bytes + 255) & ~(size_t)255;
        return p;
    };
    float* stats  = (float*)alloc(4 * sizeof(float));
    float* coef   = (float*)alloc(8 * sizeof(float));
    int*   H      = (int*)alloc((size_t)NBUCK * NBLK * sizeof(int));
    int*   boff   = (int*)alloc((size_t)(NBUCK + 1) * sizeof(int));
    int*   rowptr = (int*)alloc((size_t)(NN + 1) * sizeof(int));
    int*   srcl   = (int*)alloc((size_t)ET * sizeof(int));
    float2* es2v  = (float2*)alloc((size_t)NN * sizeof(float2));
    float2* ed2v  = (float2*)alloc((size_t)NN * sizeof(float2));
    float* Wt     = (float*)alloc((size_t)4 * 4096 * sizeof(float));
    float* Wt5    = (float*)alloc((size_t)1024 * sizeof(float));
    float* bufA   = (float*)alloc((size_t)NN * 64 * sizeof(float));   // xp fp16 rows (12.8MB used)
    float* bufB   = (float*)alloc((size_t)NN * 64 * sizeof(float));
    // aliases (dead before their hosts are written):
    unsigned* pairs = (unsigned*)bufA;                    // dead after k_bucket; bufA then holds xph
    __half* xph   = (__half*)bufA;
    f4*     agg1a = (f4*)bufB;                            // floats [0 .. 400000)
    float2* agg1s = (float2*)(bufB + 400000);             // [400000 .. 600000)
    f4*     nd1   = (f4*)(bufB + 600000);                 // [600000 .. 1000000)
    float2* ed1   = (float2*)(bufB + 1000000);            // [1000000 .. 1200000)
    (void)ws_size; (void)in_sizes; (void)n_in; (void)out_size;

    k_init<<<1, 64, 0, stream>>>(stats);
    k_bnstats<<<256, 256, 0, stream>>>(h, stats);
    k_coef<<<1, 64, 0, stream>>>(W1, as1, ad1, coef);
    k_wprep<<<64, 256, 0, stream>>>(fw1, fw2, fw3, fw4, fw5, Wt, Wt5);

    // CSR build (round-5 proven path)
    k_hist<<<NBLK, 256, 0, stream>>>(ei, H);
    k_bscan1<<<1, 1024, 0, stream>>>(H, boff);
    k_bscan2<<<NBUCK, 64, 0, stream>>>(H, boff);
    k_part<<<NBLK, 256, 0, stream>>>(ei, H, pairs);
    k_bucket<<<NBUCK, 1024, 0, stream>>>(pairs, boff, rowptr, srcl);

    // GAT layer 1 (rank-2 path)
    k_prep1<<<(NN + 255) / 256, 256, 0, stream>>>(h, stats, gam, bet, coef, nd1, ed1);
    k_gat1<<<(NN + 255) / 256, 256, 0, stream>>>(nd1, ed1, rowptr, srcl, agg1a, agg1s);

    // layer-1 finalize + layer-2 transform (writes xph=bufA fp16, es2v, ed2v)
    k_xform2f<<<(NN + 255) / 256, 256, 0, stream>>>(agg1a, agg1s, W1, b1, W2, as2, ad2,
                                                    xph, es2v, ed2v);

    // GAT layer 2: paired-edge fp16 gather (8 edges in flight per wave)
    k_gat2<<<(NN * 64) / 256, 256, 0, stream>>>(xph, es2v, ed2v, rowptr, srcl, b2, bufB);

    // MLP head
    k_mlp<<<(NN + 63) / 64, 256, 0, stream>>>(bufB, Wt, Wt5, fb1, fb2, fb3, fb4, fb5, out);
}

// Round 12
// 292.013 us; speedup vs baseline: 1.5825x; 1.0294x over previous
//
#include <hip/hip_runtime.h>
#include <hip/hip_fp16.h>
#include <math.h>

#define NN 100000
#define EE 1600000
#define ET (EE + NN)          // edges + self loops = 1,700,000
#define NEG 0.2f
#define MSTR 68               // k_mlp LDS row stride (floats)
#define SMASK 0x1FFFF

// CSR-build geometry (fused path, round-8 proven)
#define NBUCK 98              // ceil(NN/1024) buckets of 1024 dst nodes
#define NBLK 416              // ceil(ET/4096) partition blocks
#define BITEMS 4096           // items per partition block (256 thr x 16)
#define BCAP 20480            // bucket capacity (mean 17408, sigma~128)

typedef float4 f4;

// ---------------- init: stats=0, gcnt=0 ----------------
__global__ void k_init(float* stats, int* gcnt) {
    int i = threadIdx.x;
    if (i < 4) stats[i] = 0.f;
    if (i < NBUCK) gcnt[i] = 0;
}

// ---------------- BN statistics ----------------
__global__ void k_bnstats(const float* __restrict__ h, float* stats) {
    int gid = blockIdx.x * blockDim.x + threadIdx.x;
    int stride = gridDim.x * blockDim.x;
    float s0 = 0.f, s1 = 0.f, q0 = 0.f, q1 = 0.f;
    for (int i = gid; i < NN; i += stride) {
        float2 v = reinterpret_cast<const float2*>(h)[i];
        s0 += v.x; q0 += v.x * v.x;
        s1 += v.y; q1 += v.y * v.y;
    }
#pragma unroll
    for (int off = 32; off >= 1; off >>= 1) {
        s0 += __shfl_xor(s0, off);
        s1 += __shfl_xor(s1, off);
        q0 += __shfl_xor(q0, off);
        q1 += __shfl_xor(q1, off);
    }
    if ((threadIdx.x & 63) == 0) {
        atomicAdd(&stats[0], s0); atomicAdd(&stats[1], s1);
        atomicAdd(&stats[2], q0); atomicAdd(&stats[3], q1);
    }
}

// ---------------- layer-1 rank-2 attention coefficients ----------------
__global__ void k_coef(const float* __restrict__ W1, const float* __restrict__ as1,
                       const float* __restrict__ ad1, float* __restrict__ coef) {
    int t = threadIdx.x;
    if (t >= 8) return;
    int sd = t >> 2, hh = (t >> 1) & 1, i = t & 1;
    const float* a = sd ? ad1 : as1;
    float s = 0.f;
    for (int c = 0; c < 32; ++c) s += W1[(hh * 32 + c) * 2 + i] * a[hh * 32 + c];
    coef[t] = s;
}

// ---------------- pack MLP weights for wave-uniform contiguous s_load streams ----------------
__global__ void k_wprep(const float* __restrict__ w1, const float* __restrict__ w2,
                        const float* __restrict__ w3, const float* __restrict__ w4,
                        const float* __restrict__ w5,
                        float* __restrict__ Wt, float* __restrict__ Wt5) {
    int idx = blockIdx.x * blockDim.x + threadIdx.x;
    if (idx < 4 * 4096) {
        int L = idx >> 12;
        int r = idx & 4095;
        int q = r >> 10;
        int t = r & 1023;
        int i = t >> 4, j = t & 15;
        const float* W = (L == 0) ? w1 : (L == 1) ? w2 : (L == 2) ? w3 : w4;
        Wt[idx] = W[(q * 16 + j) * 64 + i];
    }
    if (idx < 1024) {
        int i = idx >> 4, c = idx & 15;
        int w = c >> 2, j = c & 3;
        int o = 3 * w + j;
        int ocnt = (w == 3) ? 2 : 3;
        Wt5[idx] = (j < ocnt) ? w5[o * 64 + i] : 0.f;
    }
}

// ---------------- fused CSR partition: LDS hist + atomic run reservation + scatter ----------------
__global__ void __launch_bounds__(256) k_fpart(const int* __restrict__ ei, int* gcnt,
                                               unsigned* __restrict__ pairs) {
    __shared__ int hist[NBUCK];
    __shared__ int cur[NBUCK];
    int tid = threadIdx.x, blk = blockIdx.x;
    if (tid < NBUCK) hist[tid] = 0;
    int ss[16], dd[16];
    int base = blk * BITEMS;
    __syncthreads();
#pragma unroll
    for (int it = 0; it < 16; ++it) {
        int i = base + it * 256 + tid;
        int s = 0, d = -1;
        if (i < ET) {
            if (i < EE) { s = ei[i]; d = ei[EE + i]; }
            else { s = d = i - EE; }
            atomicAdd(&hist[d >> 10], 1);
        }
        ss[it] = s; dd[it] = d;
    }
    __syncthreads();
    if (tid < NBUCK) cur[tid] = tid * BCAP + atomicAdd(&gcnt[tid], hist[tid]);
    __syncthreads();
#pragma unroll
    for (int it = 0; it < 16; ++it) {
        int d = dd[it];
        if (d >= 0) {
            int pos = atomicAdd(&cur[d >> 10], 1);
            pairs[pos] = (unsigned)ss[it] | ((unsigned)(d & 1023) << 17);
        }
    }
}

// ---------------- 98-entry exclusive scan -> real bucket offsets ----------------
__global__ void k_scan98(const int* __restrict__ gcnt, int* __restrict__ rboff) {
    __shared__ int sm[128];
    int tid = threadIdx.x;
    int v = (tid < NBUCK) ? gcnt[tid] : 0;
    sm[tid] = v;
    __syncthreads();
    for (int off = 1; off < 128; off <<= 1) {
        int t = (tid >= off) ? sm[tid - off] : 0;
        __syncthreads();
        sm[tid] += t;
        __syncthreads();
    }
    if (tid < NBUCK) rboff[tid] = sm[tid] - v;
    if (tid == 0) rboff[NBUCK] = ET;
}

// ---------------- per-bucket local CSR (rowptr + srcl) ----------------
__global__ void __launch_bounds__(1024) k_bucket(const unsigned* __restrict__ pairs,
                                                 const int* __restrict__ gcnt,
                                                 const int* __restrict__ rboff,
                                                 int* __restrict__ rowptr,
                                                 int* __restrict__ srcl) {
    __shared__ int sh[1024];
    __shared__ int se[1024];
    int b = blockIdx.x, tid = threadIdx.x;
    int cnt = gcnt[b];
    int ibase = b * BCAP;
    int obase = rboff[b];
    sh[tid] = 0;
    __syncthreads();
    for (int k = tid; k < cnt; k += 1024) atomicAdd(&sh[pairs[ibase + k] >> 17], 1);
    __syncthreads();
    int deg = sh[tid];
    se[tid] = deg;
    __syncthreads();
    for (int off = 1; off < 1024; off <<= 1) {
        int t = (tid >= off) ? se[tid - off] : 0;
        __syncthreads();
        se[tid] += t;
        __syncthreads();
    }
    int excl = se[tid] - deg;
    int node = (b << 10) + tid;
    if (node < NN) rowptr[node] = obase + excl;
    sh[tid] = obase + excl;     // cursor
    __syncthreads();
    for (int k = tid; k < cnt; k += 1024) {
        unsigned p = pairs[ibase + k];
        int pos = atomicAdd(&sh[p >> 17], 1);
        srcl[pos] = (int)(p & SMASK);
    }
    if (b == 0 && tid == 0) rowptr[NN] = ET;
}

// ---------------- layer-1 prep: BN apply + rank-2 attention scalars ----------------
__global__ void k_prep1(const float* __restrict__ h, const float* __restrict__ stats,
                        const float* __restrict__ gamma, const float* __restrict__ beta,
                        const float* __restrict__ coef,
                        f4* __restrict__ nd1, float2* __restrict__ ed1) {
    int n = blockIdx.x * blockDim.x + threadIdx.x;
    if (n >= NN) return;
    const float inv = 1.f / (float)NN;
    float mu0 = stats[0] * inv, mu1 = stats[1] * inv;
    float v0 = stats[2] * inv - mu0 * mu0;
    float v1 = stats[3] * inv - mu1 * mu1;
    float g0 = rsqrtf(v0 + 1e-5f) * gamma[0];
    float g1 = rsqrtf(v1 + 1e-5f) * gamma[1];
    float2 hv = reinterpret_cast<const float2*>(h)[n];
    float x0 = (hv.x - mu0) * g0 + beta[0];
    float x1 = (hv.y - mu1) * g1 + beta[1];
    nd1[n] = make_float4(x0 * coef[0] + x1 * coef[1], x0 * coef[2] + x1 * coef[3], x0, x1);
    ed1[n] = make_float2(x0 * coef[4] + x1 * coef[5], x0 * coef[6] + x1 * coef[7]);
}

// ---------------- layer-1 GAT: thread per dst, 16B gather (L2-resident 1.6MB) ----------------
__global__ void __launch_bounds__(256) k_gat1(
    const f4* __restrict__ nd1, const float2* __restrict__ ed1,
    const int* __restrict__ rowptr, const int* __restrict__ srcl,
    f4* __restrict__ agg1a, float2* __restrict__ agg1s) {
    int n = blockIdx.x * blockDim.x + threadIdx.x;
    if (n >= NN) return;
    int beg = rowptr[n], end = rowptr[n + 1];
    float2 ed = ed1[n];
    float A0 = 0.f, B0 = 0.f, S0 = 0.f, A1 = 0.f, B1 = 0.f, S1 = 0.f;
    for (int k = beg; k < end; ++k) {
        int s = srcl[k];
        f4 p = nd1[s];
        float e0 = p.x + ed.x;
        float e1 = p.y + ed.y;
        e0 = (e0 > 0.f) ? e0 : NEG * e0;
        e1 = (e1 > 0.f) ? e1 : NEG * e1;
        float w0 = __expf(e0);
        float w1 = __expf(e1);
        A0 += w0 * p.z; B0 += w0 * p.w; S0 += w0;
        A1 += w1 * p.z; B1 += w1 * p.w; S1 += w1;
    }
    agg1a[n] = make_float4(A0, B0, A1, B1);
    agg1s[n] = make_float2(S0, S1);
}

// ---------------- layer-1 finalize + linear(64->64) + layer-2 attention scalars ----------------
__global__ void k_xform2f(const f4* __restrict__ agg1a, const float2* __restrict__ agg1s,
                          const float* __restrict__ W1, const float* __restrict__ b1,
                          const float* __restrict__ W, const float* __restrict__ a_s,
                          const float* __restrict__ a_d,
                          __half* __restrict__ xph, float2* __restrict__ es2v,
                          float2* __restrict__ ed2v) {
    int n = blockIdx.x * blockDim.x + threadIdx.x;
    if (n >= NN) return;
    f4 ag = agg1a[n];
    float2 sg = agg1s[n];
    float r0 = 1.f / (sg.x + 1e-16f);
    float r1 = 1.f / (sg.y + 1e-16f);
    float x[64];
#pragma unroll
    for (int f = 0; f < 64; ++f) {
        float A = (f < 32) ? ag.x : ag.z;
        float B = (f < 32) ? ag.y : ag.w;
        float r = (f < 32) ? r0 : r1;
        x[f] = fmaxf((A * W1[2 * f] + B * W1[2 * f + 1]) * r + b1[f], 0.f);
    }
    float es0 = 0.f, es1 = 0.f, ed0 = 0.f, ed1 = 0.f;
    __half2* xo = reinterpret_cast<__half2*>(xph + (size_t)n * 64);
#pragma unroll 1
    for (int fq = 0; fq < 16; ++fq) {
        float vq[4];
#pragma unroll
        for (int j = 0; j < 4; ++j) {
            int f = 4 * fq + j;
            float acc = 0.f;
#pragma unroll
            for (int i = 0; i < 64; ++i) acc += W[f * 64 + i] * x[i];
            vq[j] = acc;
            float ts = acc * a_s[f], td = acc * a_d[f];
            if (fq < 8) { es0 += ts; ed0 += td; } else { es1 += ts; ed1 += td; }
        }
        xo[2 * fq]     = __floats2half2_rn(vq[0], vq[1]);
        xo[2 * fq + 1] = __floats2half2_rn(vq[2], vq[3]);
    }
    es2v[n] = make_float2(es0, es1);
    ed2v[n] = make_float2(ed0, ed1);
}

// ---------------- layer-2 GAT: wave per dst, PAIRED edges, 8 pairs (16 edges) in flight ----------------
__global__ void __launch_bounds__(256) k_gat2(
    const __half* __restrict__ xph, const float2* __restrict__ es2v,
    const float2* __restrict__ ed2v,
    const int* __restrict__ rowptr, const int* __restrict__ srcl,
    const float* __restrict__ bias, float* __restrict__ y) {
    int wid = (blockIdx.x * blockDim.x + threadIdx.x) >> 6;
    int lane = threadIdx.x & 63;
    if (wid >= NN) return;
    int l5 = lane & 31;            // channel pair index: channels 2*l5, 2*l5+1
    int hs = lane >> 5;            // 0: even slots, 1: odd slots
    bool headhi = l5 >= 16;        // channels >=32 -> head 1
    int ch = 2 * l5;
    float2 edp = ed2v[wid];
    float edv = headhi ? edp.y : edp.x;
    int beg = rowptr[wid], end = rowptr[wid + 1];
    float sum = 0.f, a0 = 0.f, a1 = 0.f;
    int k = beg;

#define GPAIR(kk)                                                                 \
    {                                                                             \
        int s_ = srcl[(kk) + hs];                                                 \
        float2 ep_ = es2v[s_];                                                    \
        unsigned xr_ = *reinterpret_cast<const unsigned*>(&xph[(size_t)s_ * 64 + ch]); \
        float e_ = (headhi ? ep_.y : ep_.x) + edv;                                \
        e_ = (e_ > 0.f) ? e_ : NEG * e_;                                          \
        float w_ = __expf(e_);                                                    \
        float2 xv_ = __half22float2(*reinterpret_cast<const __half2*>(&xr_));     \
        sum += w_; a0 += w_ * xv_.x; a1 += w_ * xv_.y;                            \
    }

    for (; k + 16 <= end; k += 16) {
        GPAIR(k) GPAIR(k + 2) GPAIR(k + 4) GPAIR(k + 6)
        GPAIR(k + 8) GPAIR(k + 10) GPAIR(k + 12) GPAIR(k + 14)
    }
    for (; k + 8 <= end; k += 8) {
        GPAIR(k) GPAIR(k + 2) GPAIR(k + 4) GPAIR(k + 6)
    }
    for (; k < end; k += 2) {
        int idx = k + hs;
        bool valid = idx < end;
        int s_ = srcl[valid ? idx : k];
        float2 ep_ = es2v[s_];
        unsigned xr_ = *reinterpret_cast<const unsigned*>(&xph[(size_t)s_ * 64 + ch]);
        float e_ = (headhi ? ep_.y : ep_.x) + edv;
        e_ = (e_ > 0.f) ? e_ : NEG * e_;
        float w_ = valid ? __expf(e_) : 0.f;
        float2 xv_ = __half22float2(*reinterpret_cast<const __half2*>(&xr_));
        sum += w_; a0 += w_ * xv_.x; a1 += w_ * xv_.y;
    }
#undef GPAIR

    sum += __shfl_xor(sum, 32);
    a0  += __shfl_xor(a0, 32);
    a1  += __shfl_xor(a1, 32);
    if (lane < 32) {
        float rs = 1.f / (sum + 1e-16f);
        float r0 = fmaxf(a0 * rs + bias[ch], 0.f);
        float r1 = fmaxf(a1 * rs + bias[ch + 1], 0.f);
        *reinterpret_cast<float2*>(&y[(size_t)wid * 64 + ch]) = make_float2(r0, r1);
    }
}

// ---------------- fused 5-layer MLP: 4 waves/block, wave w owns outputs [16w,16w+16) ----------------
// launch_bounds(256,6): allow ~85 VGPR so xc[16]+acc[16]+prefetch stay register-resident
__device__ __forceinline__ void mlayer(const float* __restrict__ Wq, const float* __restrict__ B,
                                       int o0, const float* __restrict__ xrow, float* acc) {
#pragma unroll
    for (int j = 0; j < 16; ++j) acc[j] = B[o0 + j];
    f4 buf0 = *reinterpret_cast<const f4*>(&xrow[0]);
    f4 buf1 = *reinterpret_cast<const f4*>(&xrow[4]);
    f4 buf2 = *reinterpret_cast<const f4*>(&xrow[8]);
    f4 buf3 = *reinterpret_cast<const f4*>(&xrow[12]);
#pragma unroll
    for (int c = 0; c < 4; ++c) {
        float xc[16];
        xc[0] = buf0.x; xc[1] = buf0.y; xc[2] = buf0.z; xc[3] = buf0.w;
        xc[4] = buf1.x; xc[5] = buf1.y; xc[6] = buf1.z; xc[7] = buf1.w;
        xc[8] = buf2.x; xc[9] = buf2.y; xc[10] = buf2.z; xc[11] = buf2.w;
        xc[12] = buf3.x; xc[13] = buf3.y; xc[14] = buf3.z; xc[15] = buf3.w;
        if (c < 3) {                       // prefetch next chunk while FMAing this one
            buf0 = *reinterpret_cast<const f4*>(&xrow[(c + 1) * 16]);
            buf1 = *reinterpret_cast<const f4*>(&xrow[(c + 1) * 16 + 4]);
            buf2 = *reinterpret_cast<const f4*>(&xrow[(c + 1) * 16 + 8]);
            buf3 = *reinterpret_cast<const f4*>(&xrow[(c + 1) * 16 + 12]);
        }
#pragma unroll
        for (int i = 0; i < 16; ++i) {
            const float* row = &Wq[(c * 16 + i) * 16];   // 64 B contiguous, wave-uniform
#pragma unroll
            for (int j = 0; j < 16; ++j) acc[j] += row[j] * xc[i];
        }
    }
}

__global__ void __launch_bounds__(256, 6) k_mlp(
    const float* __restrict__ hin,
    const float* __restrict__ Wt, const float* __restrict__ Wt5,
    const float* __restrict__ b1, const float* __restrict__ b2,
    const float* __restrict__ b3, const float* __restrict__ b4,
    const float* __restrict__ b5,
    float* __restrict__ out) {
    __shared__ float xs[64 * MSTR];
    int lane = threadIdx.x & 63;
    int w = __builtin_amdgcn_readfirstlane(threadIdx.x >> 6);
    int nodeBase = blockIdx.x * 64;
    int node = nodeBase + lane;
    int o0 = w * 16;
    const float* xrow = &xs[lane * MSTR];

#pragma unroll
    for (int i = 0; i < 4; ++i) {
        int v = threadIdx.x + 256 * i;
        int nl = v >> 4;
        int f = (v & 15) << 2;
        f4 t4 = make_float4(0.f, 0.f, 0.f, 0.f);
        if (nodeBase + nl < NN)
            t4 = reinterpret_cast<const f4*>(hin)[(size_t)(nodeBase + nl) * 16 + (v & 15)];
        *reinterpret_cast<f4*>(&xs[nl * MSTR + f]) = t4;
    }
    __syncthreads();

    float acc[16];
#define MLP_LAYER(L, Bp)                                                         \
    mlayer(Wt + ((L) * 4 + w) * 1024, Bp, o0, xrow, acc);                        \
    __syncthreads();                                                             \
    _Pragma("unroll")                                                            \
    for (int j = 0; j < 16; j += 4)                                              \
        *reinterpret_cast<f4*>(&xs[lane * MSTR + o0 + j]) =                      \
            make_float4(fmaxf(acc[j], 0.f), fmaxf(acc[j + 1], 0.f),              \
                        fmaxf(acc[j + 2], 0.f), fmaxf(acc[j + 3], 0.f));         \
    __syncthreads();

    MLP_LAYER(0, b1)
    MLP_LAYER(1, b2)
    MLP_LAYER(2, b3)
    MLP_LAYER(3, b4)
#undef MLP_LAYER

    int ocnt = (w == 3) ? 2 : 3;
    int ob = w * 3;
    float a5[3];
#pragma unroll
    for (int j = 0; j < 3; ++j) a5[j] = (j < ocnt) ? b5[ob + j] : 0.f;
#pragma unroll
    for (int c = 0; c < 4; ++c) {
        float xc[16];
#pragma unroll
        for (int q = 0; q < 4; ++q) {
            f4 t = *reinterpret_cast<const f4*>(&xrow[c * 16 + 4 * q]);
            xc[4 * q] = t.x; xc[4 * q + 1] = t.y; xc[4 * q + 2] = t.z; xc[4 * q + 3] = t.w;
        }
#pragma unroll
        for (int i = 0; i < 16; ++i) {
            const float* row = &Wt5[(c * 16 + i) * 16 + 4 * w];
#pragma unroll
            for (int j = 0; j < 3; ++j) a5[j] += row[j] * xc[i];
        }
    }
    if (node < NN) {
        for (int j = 0; j < ocnt; ++j) out[(size_t)node * 11 + ob + j] = a5[j];
    }
}

// ---------------- launch ----------------
extern "C" void kernel_launch(void* const* d_in, const int* in_sizes, int n_in,
                              void* d_out, int out_size, void* d_ws, size_t ws_size,
                              hipStream_t stream) {
    const float* h   = (const float*)d_in[0];
    const int*   ei  = (const int*)d_in[1];
    const float* gam = (const float*)d_in[2];
    const float* bet = (const float*)d_in[3];
    const float* W1  = (const float*)d_in[4];
    const float* as1 = (const float*)d_in[5];
    const float* ad1 = (const float*)d_in[6];
    const float* b1  = (const float*)d_in[7];
    const float* W2  = (const float*)d_in[8];
    const float* as2 = (const float*)d_in[9];
    const float* ad2 = (const float*)d_in[10];
    const float* b2  = (const float*)d_in[11];
    const float* fw1 = (const float*)d_in[12];
    const float* fb1 = (const float*)d_in[13];
    const float* fw2 = (const float*)d_in[14];
    const float* fb2 = (const float*)d_in[15];
    const float* fw3 = (const float*)d_in[16];
    const float* fb3 = (const float*)d_in[17];
    const float* fw4 = (const float*)d_in[18];
    const float* fb4 = (const float*)d_in[19];
    const float* fw5 = (const float*)d_in[20];
    const float* fb5 = (const float*)d_in[21];
    float* out = (float*)d_out;

    char* ws = (char*)d_ws;
    size_t off = 0;
    auto alloc = [&](size_t bytes) -> char* {
        char* p = ws + off;
        off += (bytes + 255) & ~(size_t)255;
        return p;
    };
    float* stats  = (float*)alloc(4 * sizeof(float));
    float* coef   = (float*)alloc(8 * sizeof(float));
    int*   gcnt   = (int*)alloc(NBUCK * sizeof(int));
    int*   rboff  = (int*)alloc((NBUCK + 1) * sizeof(int));
    int*   rowptr = (int*)alloc((size_t)(NN + 1) * sizeof(int));
    int*   srcl   = (int*)alloc((size_t)ET * sizeof(int));
    float2* es2v  = (float2*)alloc((size_t)NN * sizeof(float2));
    float2* ed2v  = (float2*)alloc((size_t)NN * sizeof(float2));
    float* Wt     = (float*)alloc((size_t)4 * 4096 * sizeof(float));
    float* Wt5    = (float*)alloc((size_t)1024 * sizeof(float));
    float* bufA   = (float*)alloc((size_t)NN * 64 * sizeof(float));   // pairs -> xph
    float* bufB   = (float*)alloc((size_t)NN * 64 * sizeof(float));
    // aliases (dead before their hosts are written):
    unsigned* pairs = (unsigned*)bufA;                    // 98*20480 u32 = 8MB; dead after k_bucket
    __half* xph   = (__half*)bufA;
    f4*     agg1a = (f4*)bufB;                            // floats [0 .. 400000)
    float2* agg1s = (float2*)(bufB + 400000);             // [400000 .. 600000)
    f4*     nd1   = (f4*)(bufB + 600000);                 // [600000 .. 1000000)
    float2* ed1   = (float2*)(bufB + 1000000);            // [1000000 .. 1200000)
    (void)ws_size; (void)in_sizes; (void)n_in; (void)out_size;

    k_init<<<1, 128, 0, stream>>>(stats, gcnt);
    k_bnstats<<<256, 256, 0, stream>>>(h, stats);
    k_coef<<<1, 64, 0, stream>>>(W1, as1, ad1, coef);
    k_wprep<<<64, 256, 0, stream>>>(fw1, fw2, fw3, fw4, fw5, Wt, Wt5);

    // fused CSR build (round-8 proven)
    k_fpart<<<NBLK, 256, 0, stream>>>(ei, gcnt, pairs);
    k_scan98<<<1, 128, 0, stream>>>(gcnt, rboff);
    k_bucket<<<NBUCK, 1024, 0, stream>>>(pairs, gcnt, rboff, rowptr, srcl);

    // GAT layer 1 (rank-2 path)
    k_prep1<<<(NN + 255) / 256, 256, 0, stream>>>(h, stats, gam, bet, coef, nd1, ed1);
    k_gat1<<<(NN + 255) / 256, 256, 0, stream>>>(nd1, ed1, rowptr, srcl, agg1a, agg1s);

    // layer-1 finalize + layer-2 transform (writes xph=bufA fp16, es2v, ed2v)
    k_xform2f<<<(NN + 255) / 256, 256, 0, stream>>>(agg1a, agg1s, W1, b1, W2, as2, ad2,
                                                    xph, es2v, ed2v);

    // GAT layer 2: paired-edge fp16 gather, 16 edges in flight per wave
    k_gat2<<<(NN * 64) / 256, 256, 0, stream>>>(xph, es2v, ed2v, rowptr, srcl, b2, bufB);

    // MLP head
    k_mlp<<<(NN + 63) / 64, 256, 0, stream>>>(bufB, Wt, Wt5, fb1, fb2, fb3, fb4, fb5, out);
}